// Round 2
// baseline (559.449 us; speedup 1.0000x reference)
//
#include <hip/hip_runtime.h>

// B=256 queries, D=2048, d=64 hash dim, N=100000 database, C=100 classes,
// K=1000 SMALLEST-sim selection. Inputs x/W/codes are FLOAT32 (per reference
// jnp.float32 -> "float32 -> const float*"); labels integer; output FLOAT32.
// Grading ref is numpy (f64) => reproduce the f64 top-K *set* exactly:
// one boundary flip = 1e-3 > threshold 4.8e-4. All sims computed in f64 with
// fixed fma chains (schedule-independent, identical across kernels).
//
// Pipeline:
//   k_out      : out = x@W in f64, plus ||out_b||^2
//   k_codenorm : max ||code||^2  (analytic Cauchy-Schwarz bucket range)
//   k_hist     : f64 sim GEMM -> per-row 512-bucket histogram (+u16 bucket ids)
//   k_scan     : per row: threshold bucket tb, count below, quota r=K-below
//   k_classify : bucket<tb -> label counts; bucket==tb -> candidate list
//   k_final    : exact f64 sort of candidates, take r smallest, emit probs

#define NBK 512          // buckets per row histogram
#define CAPC 2048        // candidate capacity per row (expected ~120)
#define RG 16            // rows per GEMM block
#define SCODES 8         // codes per thread per GEMM block
#define CHN (SCODES*256) // codes per block chunk = 2048
#define NCLS 100

struct Scal { int shift; unsigned cmaxsq_bits; };

// dot of code row n (f32) against 16 consecutive out rows (f64).
static __device__ __forceinline__ void dot16(const float* __restrict__ codes, int n,
                                             const double* __restrict__ outr, double acc[RG]) {
  const float4* crow = (const float4*)(codes + (size_t)n * 64);
#pragma unroll
  for (int r = 0; r < RG; ++r) acc[r] = 0.0;
#pragma unroll
  for (int t4 = 0; t4 < 4; ++t4) {
    float4 f0 = crow[t4*4+0], f1 = crow[t4*4+1], f2 = crow[t4*4+2], f3 = crow[t4*4+3];
    double c[16];
    c[0]=f0.x; c[1]=f0.y; c[2]=f0.z; c[3]=f0.w;
    c[4]=f1.x; c[5]=f1.y; c[6]=f1.z; c[7]=f1.w;
    c[8]=f2.x; c[9]=f2.y; c[10]=f2.z; c[11]=f2.w;
    c[12]=f3.x; c[13]=f3.y; c[14]=f3.z; c[15]=f3.w;
#pragma unroll
    for (int r = 0; r < RG; ++r) {
      const double* op = outr + r*64 + t4*16;   // wave-uniform -> scalar loads
#pragma unroll
      for (int j = 0; j < 16; ++j) acc[r] = fma(c[j], op[j], acc[r]);
    }
  }
}

static __device__ __forceinline__ double dot1(const float* __restrict__ codes, int n,
                                              const double* __restrict__ od) {
  const float4* crow = (const float4*)(codes + (size_t)n * 64);
  double a = 0.0;
#pragma unroll
  for (int i = 0; i < 16; ++i) {
    float4 q = crow[i];
    a = fma((double)q.x, od[i*4+0], a);
    a = fma((double)q.y, od[i*4+1], a);
    a = fma((double)q.z, od[i*4+2], a);
    a = fma((double)q.w, od[i*4+3], a);
  }
  return a;
}

static __device__ __forceinline__ int bucketOf(double v, double lo, double inv) {
  int bk = (int)((v - lo) * inv);   // monotone (trunc+clamp preserve order)
  return bk < 0 ? 0 : (bk > NBK-1 ? NBK-1 : bk);
}

// ---- detect labels layout: int64 (little-endian pairs) vs int32 ----
__global__ void k_detect(const int* __restrict__ labels, int N, Scal* scal) {
  if (threadIdx.x == 0 && blockIdx.x == 0) {
    int m = N < 256 ? N : 256;
    int is64 = 1;
    for (int i = 0; i < m; ++i) if (labels[2*i + 1] != 0) { is64 = 0; break; }
    scal->shift = is64;  // label(n) = labels[n << shift]
  }
}

// ---- max ||code_n||^2 ----
__global__ __launch_bounds__(256) void k_codenorm(const float* __restrict__ codes,
                                                  int N, Scal* scal) {
  int n = blockIdx.x * 256 + threadIdx.x;
  float m = 0.0f;
  if (n < N) {
    const float4* crow = (const float4*)(codes + (size_t)n * 64);
    double c2 = 0.0;
#pragma unroll
    for (int i = 0; i < 16; ++i) {
      float4 q = crow[i];
      c2 = fma((double)q.x, (double)q.x, c2);
      c2 = fma((double)q.y, (double)q.y, c2);
      c2 = fma((double)q.z, (double)q.z, c2);
      c2 = fma((double)q.w, (double)q.w, c2);
    }
    m = (float)(c2 * 1.000001);
  }
  __shared__ float red[256];
  red[threadIdx.x] = m; __syncthreads();
  for (int off = 128; off > 0; off >>= 1) {
    if (threadIdx.x < off) red[threadIdx.x] = fmaxf(red[threadIdx.x], red[threadIdx.x + off]);
    __syncthreads();
  }
  if (threadIdx.x == 0) atomicMax(&scal->cmaxsq_bits, __float_as_uint(red[0]));
}

// ---- out = x @ W in f64, plus ||out_b||^2 ----
__global__ __launch_bounds__(256) void k_out(const float* __restrict__ x,
                                             const float* __restrict__ W, int D,
                                             double* __restrict__ out64, double* __restrict__ B1sq) {
  int b = blockIdx.x, tid = threadIdx.x;
  int t = tid & 63, w = tid >> 6;
  int kc = D >> 2;
  double acc = 0.0;
  const float* xr = x + (size_t)b * D;
  for (int k = w * kc; k < (w + 1) * kc; ++k)
    acc = fma((double)xr[k], (double)W[(size_t)k * 64 + t], acc);
  __shared__ double red[256];
  red[tid] = acc; __syncthreads();
  double o = 0.0;
  if (w == 0) {
    o = red[t] + red[64 + t] + red[128 + t] + red[192 + t];
    out64[(size_t)b * 64 + t] = o;
  }
  __syncthreads();
  if (w == 0) red[t] = o * o;
  __syncthreads();
  if (tid == 0) {
    double s = 0.0;
    for (int i = 0; i < 64; ++i) s += red[i];
    B1sq[b] = s;
  }
}

// ---- f64 sim GEMM + per-row bucket histograms (+ optional u16 bucket ids) ----
__global__ __launch_bounds__(256) void k_hist(const float* __restrict__ codes,
                                              const double* __restrict__ out64,
                                              const double* __restrict__ B1sq,
                                              const Scal* __restrict__ scal, int N, int B,
                                              unsigned* __restrict__ histg,
                                              unsigned short* __restrict__ ids, int use_ids) {
  __shared__ unsigned hist[RG * NBK];    // 32 KB
  __shared__ double rowLo[RG], rowInv[RG];
  int tid = threadIdx.x;
  int r0 = blockIdx.y * RG;
  for (int i = tid; i < RG * NBK; i += 256) hist[i] = 0u;
  if (tid < RG) {
    double hr = 0.5 * sqrt(B1sq[r0 + tid] * (double)__uint_as_float(scal->cmaxsq_bits)) + 1.0;
    rowLo[tid] = 50.0 - hr;
    rowInv[tid] = (double)NBK / (2.0 * hr);
  }
  __syncthreads();
  const double* outr = out64 + (size_t)r0 * 64;
  for (int s = 0; s < SCODES; ++s) {
    int n = blockIdx.x * CHN + s * 256 + tid;
    bool valid = n < N;
    int nc = valid ? n : (N - 1);
    double acc[RG];
    dot16(codes, nc, outr, acc);
    if (valid) {
#pragma unroll
      for (int r = 0; r < RG; ++r) {
        double v = fma(acc[r], -0.5, 50.0);
        int bk = bucketOf(v, rowLo[r], rowInv[r]);
        atomicAdd(&hist[r * NBK + bk], 1u);
        if (use_ids) ids[(size_t)(r0 + r) * N + n] = (unsigned short)bk;
      }
    }
  }
  __syncthreads();
  for (int i = tid; i < RG * NBK; i += 256)
    if (hist[i]) atomicAdd(&histg[(size_t)(r0 + i / NBK) * NBK + (i % NBK)], hist[i]);
}

// ---- per-row: threshold bucket, count below, quota ----
__global__ __launch_bounds__(256) void k_scan(const unsigned* __restrict__ histg,
                                              int B, const int* __restrict__ Kp,
                                              int4* __restrict__ rowinfo) {
  int b = blockIdx.x;
  if (threadIdx.x == 0) {
    const unsigned* h = histg + (size_t)b * NBK;
    int K = Kp[0];
    unsigned cum = 0; int tb = NBK - 1; int cb = 0;
    for (int i = 0; i < NBK; ++i) {
      if (cum + h[i] >= (unsigned)K) { tb = i; cb = (int)cum; break; }
      cum += h[i];
    }
    rowinfo[b] = make_int4(tb, cb, K - cb, 0);
  }
}

// ---- classify via stored bucket ids (fast path) ----
__global__ __launch_bounds__(256) void k_classify_ids(const unsigned short* __restrict__ ids, int N,
                                                      const int4* __restrict__ rowinfo,
                                                      const int* __restrict__ labels,
                                                      const Scal* __restrict__ scal,
                                                      unsigned* __restrict__ belowCnt,
                                                      unsigned* __restrict__ candCnt,
                                                      unsigned* __restrict__ cand) {
  __shared__ unsigned lab[NCLS];
  int b = blockIdx.y, tid = threadIdx.x;
  for (int i = tid; i < NCLS; i += 256) lab[i] = 0u;
  __syncthreads();
  int tb = rowinfo[b].x;
  int shift = scal->shift;
  int chunk = (N + gridDim.x - 1) / gridDim.x;
  int start = blockIdx.x * chunk;
  int end = start + chunk; if (end > N) end = N;
  const unsigned short* idr = ids + (size_t)b * N;
  for (int n = start + tid; n < end; n += 256) {
    int id = idr[n];
    if (id < tb) {
      atomicAdd(&lab[labels[(size_t)n << shift]], 1u);
    } else if (id == tb) {
      unsigned pos = atomicAdd(&candCnt[b], 1u);
      if (pos < CAPC) cand[(size_t)b * CAPC + pos] = (unsigned)n;
    }
  }
  __syncthreads();
  for (int i = tid; i < NCLS; i += 256) if (lab[i]) atomicAdd(&belowCnt[b * NCLS + i], lab[i]);
}

// ---- classify by recomputing sims (fallback when ws too small for ids) ----
__global__ __launch_bounds__(256) void k_classify_rc(const float* __restrict__ codes,
                                                     const double* __restrict__ out64,
                                                     const double* __restrict__ B1sq,
                                                     const Scal* __restrict__ scal, int N, int B,
                                                     const int4* __restrict__ rowinfo,
                                                     const int* __restrict__ labels,
                                                     unsigned* __restrict__ belowCnt,
                                                     unsigned* __restrict__ candCnt,
                                                     unsigned* __restrict__ cand) {
  __shared__ unsigned lab[RG * NCLS];
  __shared__ double rowLo[RG], rowInv[RG];
  __shared__ int tbs[RG];
  int tid = threadIdx.x;
  int r0 = blockIdx.y * RG;
  for (int i = tid; i < RG * NCLS; i += 256) lab[i] = 0u;
  if (tid < RG) {
    double hr = 0.5 * sqrt(B1sq[r0 + tid] * (double)__uint_as_float(scal->cmaxsq_bits)) + 1.0;
    rowLo[tid] = 50.0 - hr;
    rowInv[tid] = (double)NBK / (2.0 * hr);
    tbs[tid] = rowinfo[r0 + tid].x;
  }
  __syncthreads();
  int shift = scal->shift;
  const double* outr = out64 + (size_t)r0 * 64;
  for (int s = 0; s < SCODES; ++s) {
    int n = blockIdx.x * CHN + s * 256 + tid;
    bool valid = n < N;
    int nc = valid ? n : (N - 1);
    double acc[RG];
    dot16(codes, nc, outr, acc);
    if (valid) {
#pragma unroll
      for (int r = 0; r < RG; ++r) {
        double v = fma(acc[r], -0.5, 50.0);
        int bk = bucketOf(v, rowLo[r], rowInv[r]);
        if (bk < tbs[r]) {
          atomicAdd(&lab[r * NCLS + labels[(size_t)n << shift]], 1u);
        } else if (bk == tbs[r]) {
          unsigned pos = atomicAdd(&candCnt[r0 + r], 1u);
          if (pos < CAPC) cand[(size_t)(r0 + r) * CAPC + pos] = (unsigned)n;
        }
      }
    }
  }
  __syncthreads();
  for (int i = tid; i < RG * NCLS; i += 256)
    if (lab[i]) atomicAdd(&belowCnt[(size_t)(r0 + i / NCLS) * NCLS + (i % NCLS)], lab[i]);
}

// ---- boundary resolve: exact f64 sort of threshold-bucket candidates ----
__global__ __launch_bounds__(256) void k_final(const float* __restrict__ codes,
                                               const double* __restrict__ out64,
                                               const int4* __restrict__ rowinfo,
                                               const unsigned* __restrict__ candCnt,
                                               const unsigned* __restrict__ cand,
                                               const Scal* __restrict__ scal,
                                               const int* __restrict__ labels,
                                               const unsigned* __restrict__ belowCnt,
                                               const int* __restrict__ Kp,
                                               float* __restrict__ outp, int N) {
  __shared__ double key[CAPC];
  __shared__ int kidx[CAPC];
  __shared__ unsigned lab[NCLS];
  int b = blockIdx.x, tid = threadIdx.x;
  int cnt = (int)candCnt[b]; if (cnt > CAPC) cnt = CAPC;
  int need = rowinfo[b].z;
  int M = 1; while (M < cnt) M <<= 1;
  const double* od = out64 + (size_t)b * 64;
  for (int i = tid; i < M; i += 256) {
    if (i < cnt) {
      int n = (int)cand[(size_t)b * CAPC + i];
      key[i] = fma(dot1(codes, n, od), -0.5, 50.0);
      kidx[i] = n;
    } else { key[i] = __builtin_inf(); kidx[i] = 0x7FFFFFFF; }
  }
  __syncthreads();
  for (int size = 2; size <= M; size <<= 1) {
    for (int stride = size >> 1; stride > 0; stride >>= 1) {
      for (int i = tid; i < M; i += 256) {
        int j = i ^ stride;
        if (j > i) {
          double ki = key[i], kj = key[j];
          int ii = kidx[i], ij = kidx[j];
          bool up = ((i & size) == 0);
          bool sw = up ? (kj < ki || (kj == ki && ij < ii))
                       : (kj > ki || (kj == ki && ij > ii));
          if (sw) { key[i] = kj; key[j] = ki; kidx[i] = ij; kidx[j] = ii; }
        }
      }
      __syncthreads();
    }
  }
  for (int i = tid; i < NCLS; i += 256) lab[i] = 0u;
  __syncthreads();
  int shift = scal->shift;
  int take = need < cnt ? need : cnt;
  for (int i = tid; i < take; i += 256)
    atomicAdd(&lab[labels[(size_t)kidx[i] << shift]], 1u);
  __syncthreads();
  double Kd = (double)Kp[0];
  for (int c = tid; c < NCLS; c += 256)
    outp[b * NCLS + c] = (float)((double)(belowCnt[b * NCLS + c] + lab[c]) / Kd);
}

extern "C" void kernel_launch(void* const* d_in, const int* in_sizes, int n_in,
                              void* d_out, int out_size, void* d_ws, size_t ws_size,
                              hipStream_t stream) {
  const float* x     = (const float*)d_in[0];
  const float* W     = (const float*)d_in[1];
  const float* codes = (const float*)d_in[2];
  const int* labels  = (const int*)d_in[3];
  const int* Kp      = (const int*)d_in[4];

  const int B = out_size / NCLS;        // 256
  const int N = in_sizes[3];            // 100000
  const int D = in_sizes[0] / B;        // 2048
  const int NCH = (N + CHN - 1) / CHN;  // 49

  char* p = (char*)d_ws;
  double* out64      = (double*)p;   p += (size_t)B * 64 * sizeof(double);   // 128 KB
  double* B1sq       = (double*)p;   p += (size_t)B * sizeof(double);        // 2 KB
  Scal* scal         = (Scal*)p;     p += 64;
  int4* rowinfo      = (int4*)p;     p += (size_t)B * sizeof(int4);          // 4 KB
  unsigned* belowCnt = (unsigned*)p; p += (size_t)B * NCLS * sizeof(unsigned); // 100 KB
  unsigned* candCnt  = (unsigned*)p; p += (size_t)B * sizeof(unsigned);      // 1 KB
  unsigned* cand     = (unsigned*)p; p += (size_t)B * CAPC * sizeof(unsigned); // 2 MB
  unsigned* histg    = (unsigned*)p; p += (size_t)B * NBK * sizeof(unsigned);  // 512 KB
  size_t base_need = (size_t)(p - (char*)d_ws);
  unsigned short* ids = (unsigned short*)p;                                  // 51.2 MB opt
  int use_ids = (ws_size >= base_need + (size_t)B * N * 2) ? 1 : 0;

  hipMemsetAsync(scal, 0, 64, stream);
  hipMemsetAsync(belowCnt, 0, (size_t)B * NCLS * 4, stream);
  hipMemsetAsync(candCnt, 0, (size_t)B * 4, stream);
  hipMemsetAsync(histg, 0, (size_t)B * NBK * 4, stream);

  k_detect<<<1, 64, 0, stream>>>(labels, N, scal);
  k_codenorm<<<(N + 255) / 256, 256, 0, stream>>>(codes, N, scal);
  k_out<<<B, 256, 0, stream>>>(x, W, D, out64, B1sq);
  k_hist<<<dim3(NCH, B / RG), 256, 0, stream>>>(codes, out64, B1sq, scal, N, B,
                                                histg, ids, use_ids);
  k_scan<<<B, 256, 0, stream>>>(histg, B, Kp, rowinfo);
  if (use_ids) {
    k_classify_ids<<<dim3(8, B), 256, 0, stream>>>(ids, N, rowinfo, labels, scal,
                                                   belowCnt, candCnt, cand);
  } else {
    k_classify_rc<<<dim3(NCH, B / RG), 256, 0, stream>>>(codes, out64, B1sq, scal, N, B,
                                                         rowinfo, labels, belowCnt, candCnt, cand);
  }
  k_final<<<B, 256, 0, stream>>>(codes, out64, rowinfo, candCnt, cand, scal, labels,
                                 belowCnt, Kp, (float*)d_out, N);
}

// Round 3
// 533.548 us; speedup vs baseline: 1.0485x; 1.0485x over previous
//
#include <hip/hip_runtime.h>
#include <hip/hip_fp16.h>

// B=256 queries, D=2048, d=64 hash dim, N=100000 database, C=100 classes,
// K=1000 SMALLEST-sim selection. Inputs f32, labels int, output f32.
// Strategy: f32 screening GEMM with rigorous per-row error bound M
// (|v64 - h| <= M where h = f16(store) of the f32 fma-chain sim):
//   h <  TL = lo_tb - 2M  =>  definitely in top-K   (label-counted)
//   h >  TH = hi_tb + 2M  =>  definitely NOT in top-K
//   else                  =>  candidate (~260/row), resolved by exact f64 sims
// Result set == exact f64 top-K (same as the R2 full-f64 kernel; absmax was 0).

#define NBK 512          // buckets per row histogram
#define CAPC 1024        // candidate capacity per row (expected ~260)
#define RG 32            // out-rows per k_sim block
#define SCODES 2         // codes per thread per k_sim block
#define CHN (SCODES*256) // codes per block chunk = 512
#define NCLS 100

struct Scal { int shift; unsigned cmaxsq_bits; };

static __device__ __forceinline__ unsigned short f2h(float v) {
  __half h = __float2half(v);            // round-to-nearest-even
  unsigned short u; __builtin_memcpy(&u, &h, 2); return u;
}
static __device__ __forceinline__ float h2f(unsigned short u) {
  __half h; __builtin_memcpy(&h, &u, 2); return __half2float(h);
}

static __device__ __forceinline__ int bucketOf(double v, double lo, double inv) {
  int bk = (int)((v - lo) * inv);        // monotone; clamp edges
  return bk < 0 ? 0 : (bk > NBK - 1 ? NBK - 1 : bk);
}

// identical expression in k_rowhist and k_scan; any 1-ulp discrepancy is
// absorbed by the 2M margins (M >= 0.01 >> 1e-10).
static __device__ __forceinline__ void rowRange(double b1sq, double cmax,
                                                double& lo, double& inv, double& bw) {
  double hr = 0.5 * sqrt(b1sq * cmax) * 1.000001 + 9.0;  // +9 covers f32+f16 err beyond range
  lo = 50.0 - hr;
  bw = (2.0 * hr) / (double)NBK;
  inv = (double)NBK / (2.0 * hr);
}

// exact f64 dot for candidate resolution (order-stable chain)
static __device__ __forceinline__ double dot1(const float* __restrict__ codes, int n,
                                              const double* __restrict__ od) {
  const float4* crow = (const float4*)(codes + (size_t)n * 64);
  double a = 0.0;
#pragma unroll
  for (int i = 0; i < 16; ++i) {
    float4 q = crow[i];
    a = fma((double)q.x, od[i*4+0], a);
    a = fma((double)q.y, od[i*4+1], a);
    a = fma((double)q.z, od[i*4+2], a);
    a = fma((double)q.w, od[i*4+3], a);
  }
  return a;
}

// ---- detect labels layout: int64 (little-endian pairs) vs int32 ----
__global__ void k_detect(const int* __restrict__ labels, int N, Scal* scal) {
  if (threadIdx.x == 0 && blockIdx.x == 0) {
    int m = N < 256 ? N : 256;
    int is64 = 1;
    for (int i = 0; i < m; ++i) if (labels[2*i + 1] != 0) { is64 = 0; break; }
    scal->shift = is64;  // label(n) = labels[n << shift]
  }
}

// ---- max ||code_n||^2 ----
__global__ __launch_bounds__(256) void k_codenorm(const float* __restrict__ codes,
                                                  int N, Scal* scal) {
  int n = blockIdx.x * 256 + threadIdx.x;
  float m = 0.0f;
  if (n < N) {
    const float4* crow = (const float4*)(codes + (size_t)n * 64);
    double c2 = 0.0;
#pragma unroll
    for (int i = 0; i < 16; ++i) {
      float4 q = crow[i];
      c2 = fma((double)q.x, (double)q.x, c2);
      c2 = fma((double)q.y, (double)q.y, c2);
      c2 = fma((double)q.z, (double)q.z, c2);
      c2 = fma((double)q.w, (double)q.w, c2);
    }
    m = (float)(c2 * 1.000001);
  }
  __shared__ float red[256];
  red[threadIdx.x] = m; __syncthreads();
  for (int off = 128; off > 0; off >>= 1) {
    if (threadIdx.x < off) red[threadIdx.x] = fmaxf(red[threadIdx.x], red[threadIdx.x + off]);
    __syncthreads();
  }
  if (threadIdx.x == 0) atomicMax(&scal->cmaxsq_bits, __float_as_uint(red[0]));
}

// ---- out = x @ W in f64 (+ f32 copy for screening), plus ||out_b||^2 ----
__global__ __launch_bounds__(256) void k_out(const float* __restrict__ x,
                                             const float* __restrict__ W, int D,
                                             double* __restrict__ out64,
                                             float* __restrict__ out32,
                                             double* __restrict__ B1sq) {
  int b = blockIdx.x, tid = threadIdx.x;
  int t = tid & 63, w = tid >> 6;
  int kc = D >> 2;
  double acc = 0.0;
  const float* xr = x + (size_t)b * D;
  for (int k = w * kc; k < (w + 1) * kc; ++k)
    acc = fma((double)xr[k], (double)W[(size_t)k * 64 + t], acc);
  __shared__ double red[256];
  red[tid] = acc; __syncthreads();
  double o = 0.0;
  if (w == 0) {
    o = red[t] + red[64 + t] + red[128 + t] + red[192 + t];
    out64[(size_t)b * 64 + t] = o;
    out32[(size_t)b * 64 + t] = (float)o;
  }
  __syncthreads();
  if (w == 0) red[t] = o * o;
  __syncthreads();
  if (tid == 0) {
    double s = 0.0;
    for (int i = 0; i < 64; ++i) s += red[i];
    B1sq[b] = s;
  }
}

// ---- f32 screening GEMM -> f16 scores (no LDS; out-rows via scalar broadcast) ----
__global__ __launch_bounds__(256) void k_sim(const float* __restrict__ codes,
                                             const float* __restrict__ out32,
                                             int N, unsigned short* __restrict__ simh) {
  const int tid = threadIdx.x;
  const int r0 = blockIdx.y * RG;
  const float* __restrict__ outr = out32 + (size_t)r0 * 64;
  for (int s = 0; s < SCODES; ++s) {
    const int n = blockIdx.x * CHN + s * 256 + tid;
    if (n >= N) continue;
    const float4* __restrict__ crow = (const float4*)(codes + (size_t)n * 64);
    float acc[RG];
#pragma unroll
    for (int r = 0; r < RG; ++r) acc[r] = 0.0f;
#pragma unroll 1
    for (int t4 = 0; t4 < 4; ++t4) {         // rolled: keeps loop body I$-resident
      float4 f0 = crow[t4*4+0], f1 = crow[t4*4+1], f2 = crow[t4*4+2], f3 = crow[t4*4+3];
      float c[16] = {f0.x,f0.y,f0.z,f0.w, f1.x,f1.y,f1.z,f1.w,
                     f2.x,f2.y,f2.z,f2.w, f3.x,f3.y,f3.z,f3.w};
#pragma unroll
      for (int r = 0; r < RG; ++r) {
        const float* __restrict__ op = outr + r * 64 + t4 * 16;  // wave-uniform -> s_load
#pragma unroll
        for (int j = 0; j < 16; ++j) acc[r] = fmaf(c[j], op[j], acc[r]);
      }
    }
#pragma unroll
    for (int r = 0; r < RG; ++r) {
      float v = fmaf(acc[r], -0.5f, 50.0f);
      simh[(size_t)(r0 + r) * N + n] = f2h(v);
    }
  }
}

// ---- per-row 512-bucket histogram of stored f16 scores ----
__global__ __launch_bounds__(256) void k_rowhist(const unsigned short* __restrict__ simh, int N,
                                                 const double* __restrict__ B1sq,
                                                 const Scal* __restrict__ scal,
                                                 unsigned* __restrict__ histg) {
  __shared__ unsigned hist[NBK];
  int b = blockIdx.x, tid = threadIdx.x;
  for (int i = tid; i < NBK; i += 256) hist[i] = 0u;
  __syncthreads();
  double lo, inv, bw;
  rowRange(B1sq[b], (double)__uint_as_float(scal->cmaxsq_bits), lo, inv, bw);
  const unsigned short* rp = simh + (size_t)b * N;
  const uint4* rp4 = (const uint4*)rp;
  int n8 = N >> 3;
  for (int i = tid; i < n8; i += 256) {
    uint4 q = rp4[i];
    unsigned u[4] = {q.x, q.y, q.z, q.w};
#pragma unroll
    for (int k = 0; k < 4; ++k) {
      atomicAdd(&hist[bucketOf((double)h2f((unsigned short)(u[k] & 0xFFFFu)), lo, inv)], 1u);
      atomicAdd(&hist[bucketOf((double)h2f((unsigned short)(u[k] >> 16)), lo, inv)], 1u);
    }
  }
  for (int n = (n8 << 3) + tid; n < N; n += 256)
    atomicAdd(&hist[bucketOf((double)h2f(rp[n]), lo, inv)], 1u);
  __syncthreads();
  for (int i = tid; i < NBK; i += 256) histg[(size_t)b * NBK + i] = hist[i];
}

// ---- per-row: threshold bucket -> conservative [TL, TH] window ----
__global__ __launch_bounds__(256) void k_scan(const unsigned* __restrict__ histg, int B,
                                              const double* __restrict__ B1sq,
                                              const Scal* __restrict__ scal,
                                              const int* __restrict__ Kp,
                                              double2* __restrict__ rowTH) {
  int b = blockIdx.x * 256 + threadIdx.x;
  if (b >= B) return;
  int K = Kp[0];
  const unsigned* h = histg + (size_t)b * NBK;
  unsigned cum = 0; int tb = NBK - 1;
  for (int i = 0; i < NBK; ++i) {
    unsigned c = h[i];
    if (cum + c >= (unsigned)K) { tb = i; break; }
    cum += c;
  }
  double cmax = (double)__uint_as_float(scal->cmaxsq_bits);
  double lo, inv, bw; rowRange(B1sq[b], cmax, lo, inv, bw);
  double S = sqrt(B1sq[b] * cmax);
  // M bounds |v64 - h|: f32 fma-chain (gamma_63 ~3.8e-6, 2x slack) + f16 ulp (2x slack) + slop
  double M = 0.5 * S * 8e-6 + (50.0 + 0.55 * S) * 0x1p-10 + 0.01;
  double lot = lo + (double)tb * bw;
  rowTH[b] = make_double2(lot - 2.0 * M, lot + bw + 2.0 * M);
}

// ---- stream scores: below -> label hist; band -> candidates ----
__global__ __launch_bounds__(256) void k_classify(const unsigned short* __restrict__ simh, int N,
                                                  const double2* __restrict__ rowTH,
                                                  const int* __restrict__ labels,
                                                  const Scal* __restrict__ scal,
                                                  unsigned* __restrict__ belowCnt,
                                                  unsigned* __restrict__ belowTot,
                                                  unsigned* __restrict__ candCnt,
                                                  unsigned* __restrict__ cand) {
  __shared__ unsigned lab[NCLS];
  int b = blockIdx.y, tid = threadIdx.x;
  for (int i = tid; i < NCLS; i += 256) lab[i] = 0u;
  __syncthreads();
  double TL = rowTH[b].x, TH = rowTH[b].y;
  int shift = scal->shift;
  int nch = gridDim.x;
  int chunk = ((N + nch * 8 - 1) / (nch * 8)) * 8;   // chunk multiple of 8
  int start = blockIdx.x * chunk;
  int end = start + chunk; if (end > N) end = N;
  const unsigned short* rp = simh + (size_t)b * N;
  const uint4* rp4 = (const uint4*)rp;
  if (start < N) {
    int i8s = start >> 3, i8e = end >> 3;
    for (int i = i8s + tid; i < i8e; i += 256) {
      uint4 q = rp4[i];
      unsigned u[4] = {q.x, q.y, q.z, q.w};
#pragma unroll
      for (int k = 0; k < 8; ++k) {
        unsigned short us = (unsigned short)((u[k >> 1] >> ((k & 1) * 16)) & 0xFFFFu);
        double hv = (double)h2f(us);
        int n = i * 8 + k;
        if (hv < TL) {
          atomicAdd(&lab[labels[(size_t)n << shift]], 1u);
        } else if (hv <= TH) {
          unsigned pos = atomicAdd(&candCnt[b], 1u);
          if (pos < CAPC) cand[(size_t)b * CAPC + pos] = (unsigned)n;
        }
      }
    }
    int tail = (end & ~7); if (tail < start) tail = start;
    for (int n = tail + tid; n < end; n += 256) {
      double hv = (double)h2f(rp[n]);
      if (hv < TL) {
        atomicAdd(&lab[labels[(size_t)n << shift]], 1u);
      } else if (hv <= TH) {
        unsigned pos = atomicAdd(&candCnt[b], 1u);
        if (pos < CAPC) cand[(size_t)b * CAPC + pos] = (unsigned)n;
      }
    }
  }
  __syncthreads();
  for (int i = tid; i < NCLS; i += 256) {
    unsigned c = lab[i];
    if (c) { atomicAdd(&belowCnt[b * NCLS + i], c); atomicAdd(&belowTot[b], c); }
  }
}

// ---- exact f64 resolve of candidates + emit probs ----
__global__ __launch_bounds__(256) void k_final(const float* __restrict__ codes,
                                               const double* __restrict__ out64,
                                               const unsigned* __restrict__ candCnt,
                                               const unsigned* __restrict__ cand,
                                               const Scal* __restrict__ scal,
                                               const int* __restrict__ labels,
                                               const unsigned* __restrict__ belowCnt,
                                               const unsigned* __restrict__ belowTot,
                                               const int* __restrict__ Kp,
                                               float* __restrict__ outp, int N) {
  __shared__ double key[CAPC];
  __shared__ int kidx[CAPC];
  __shared__ unsigned lab[NCLS];
  int b = blockIdx.x, tid = threadIdx.x;
  int cnt = (int)candCnt[b]; if (cnt > CAPC) cnt = CAPC;
  int K = Kp[0];
  int need = K - (int)belowTot[b];
  int M = 1; while (M < cnt) M <<= 1;
  const double* od = out64 + (size_t)b * 64;
  for (int i = tid; i < M; i += 256) {
    if (i < cnt) {
      int n = (int)cand[(size_t)b * CAPC + i];
      key[i] = fma(dot1(codes, n, od), -0.5, 50.0);
      kidx[i] = n;
    } else { key[i] = __builtin_inf(); kidx[i] = 0x7FFFFFFF; }
  }
  __syncthreads();
  for (int size = 2; size <= M; size <<= 1) {
    for (int stride = size >> 1; stride > 0; stride >>= 1) {
      for (int i = tid; i < M; i += 256) {
        int j = i ^ stride;
        if (j > i) {
          double ki = key[i], kj = key[j];
          int ii = kidx[i], ij = kidx[j];
          bool up = ((i & size) == 0);
          bool sw = up ? (kj < ki || (kj == ki && ij < ii))
                       : (kj > ki || (kj == ki && ij > ii));
          if (sw) { key[i] = kj; key[j] = ki; kidx[i] = ij; kidx[j] = ii; }
        }
      }
      __syncthreads();
    }
  }
  for (int i = tid; i < NCLS; i += 256) lab[i] = 0u;
  __syncthreads();
  int shift = scal->shift;
  int take = need < cnt ? need : cnt;
  for (int i = tid; i < take; i += 256)
    atomicAdd(&lab[labels[(size_t)kidx[i] << shift]], 1u);
  __syncthreads();
  double Kd = (double)K;
  for (int c = tid; c < NCLS; c += 256)
    outp[b * NCLS + c] = (float)((double)(belowCnt[b * NCLS + c] + lab[c]) / Kd);
}

extern "C" void kernel_launch(void* const* d_in, const int* in_sizes, int n_in,
                              void* d_out, int out_size, void* d_ws, size_t ws_size,
                              hipStream_t stream) {
  const float* x     = (const float*)d_in[0];
  const float* W     = (const float*)d_in[1];
  const float* codes = (const float*)d_in[2];
  const int* labels  = (const int*)d_in[3];
  const int* Kp      = (const int*)d_in[4];

  const int B = out_size / NCLS;        // 256
  const int N = in_sizes[3];            // 100000
  const int D = in_sizes[0] / B;        // 2048

  // ws layout (all block sizes multiples of 64B; simh row stride 2N bytes, 16B-aligned)
  char* p = (char*)d_ws;
  double* out64      = (double*)p;   p += (size_t)B * 64 * sizeof(double);     // 128 KB
  double2* rowTH     = (double2*)p;  p += (size_t)B * sizeof(double2);         // 4 KB
  float* out32       = (float*)p;    p += (size_t)B * 64 * sizeof(float);      // 64 KB
  double* B1sq       = (double*)p;   p += (size_t)B * sizeof(double);          // 2 KB
  Scal* scal         = (Scal*)p;     p += 64;
  unsigned* belowCnt = (unsigned*)p; p += (size_t)B * NCLS * sizeof(unsigned); // 100 KB
  unsigned* belowTot = (unsigned*)p; p += (size_t)B * sizeof(unsigned);        // 1 KB
  unsigned* candCnt  = (unsigned*)p; p += (size_t)B * sizeof(unsigned);        // 1 KB
  unsigned* cand     = (unsigned*)p; p += (size_t)B * CAPC * sizeof(unsigned); // 1 MB
  unsigned* histg    = (unsigned*)p; p += (size_t)B * NBK * sizeof(unsigned);  // 512 KB
  unsigned short* simh = (unsigned short*)p;                                   // 51.2 MB

  hipMemsetAsync(scal, 0, 64, stream);
  hipMemsetAsync(belowCnt, 0, (size_t)B * NCLS * 4, stream);
  hipMemsetAsync(belowTot, 0, (size_t)B * 4, stream);
  hipMemsetAsync(candCnt, 0, (size_t)B * 4, stream);

  k_detect<<<1, 64, 0, stream>>>(labels, N, scal);
  k_codenorm<<<(N + 255) / 256, 256, 0, stream>>>(codes, N, scal);
  k_out<<<B, 256, 0, stream>>>(x, W, D, out64, out32, B1sq);
  k_sim<<<dim3((N + CHN - 1) / CHN, B / RG), 256, 0, stream>>>(codes, out32, N, simh);
  k_rowhist<<<B, 256, 0, stream>>>(simh, N, B1sq, scal, histg);
  k_scan<<<(B + 255) / 256, 256, 0, stream>>>(histg, B, B1sq, scal, Kp, rowTH);
  k_classify<<<dim3(8, B), 256, 0, stream>>>(simh, N, rowTH, labels, scal,
                                             belowCnt, belowTot, candCnt, cand);
  k_final<<<B, 256, 0, stream>>>(codes, out64, candCnt, cand, scal, labels,
                                 belowCnt, belowTot, Kp, (float*)d_out, N);
}

// Round 4
// 516.243 us; speedup vs baseline: 1.0837x; 1.0335x over previous
//
#include <hip/hip_runtime.h>
#include <hip/hip_fp16.h>

// B=256 queries, D=2048, d=64 hash dim, N=100000 database, C=100 classes,
// K=1000 SMALLEST-sim selection. Inputs f32, labels int, output f32.
// Strategy: f32 screening GEMM -> f16 scores with rigorous per-row error
// bound M (|v64 - h| <= M):
//   h <  TL  =>  definitely in top-K   (label-counted)
//   h >  TH  =>  definitely NOT in top-K
//   else     =>  candidate (~230/row), resolved by exact f64 sims
// Result set == exact f64 top-K (R2 full-f64 and R3 both gave absmax 0).

#define NBK 512          // buckets per row histogram
#define CAPC 1024        // candidate capacity per row (expected ~230)
#define RG 64            // out-rows per k_sim block (codes re-read = B/RG = 4x)
#define SCODES 2         // codes per thread per k_sim block
#define CHN (SCODES*256) // codes per block chunk = 512
#define NHCH 4           // row-chunks in k_rowhist
#define NCLS 100

struct Scal { int shift; unsigned cmaxsq_bits; };

static __device__ __forceinline__ unsigned short f2h(float v) {
  __half h = __float2half(v);            // round-to-nearest-even
  unsigned short u; __builtin_memcpy(&u, &h, 2); return u;
}
static __device__ __forceinline__ float h2f(unsigned short u) {
  __half h; __builtin_memcpy(&h, &u, 2); return __half2float(h);
}

static __device__ __forceinline__ int bucketOf(double v, double lo, double inv) {
  int bk = (int)((v - lo) * inv);        // monotone; clamp edges
  return bk < 0 ? 0 : (bk > NBK - 1 ? NBK - 1 : bk);
}

// identical expression in k_rowhist and k_scan; 1-ulp discrepancies are
// absorbed by the 2M margins (M ~ 2 >> 1e-10).
static __device__ __forceinline__ void rowRange(double b1sq, double cmax,
                                                double& lo, double& inv, double& bw) {
  double hr = 0.5 * sqrt(b1sq * cmax) * 1.000001 + 9.0;  // +9 covers f32+f16 err beyond range
  lo = 50.0 - hr;
  bw = (2.0 * hr) / (double)NBK;
  inv = (double)NBK / (2.0 * hr);
}

// exact f64 dot for candidate resolution (order-stable chain)
static __device__ __forceinline__ double dot1(const float* __restrict__ codes, int n,
                                              const double* __restrict__ od) {
  const float4* crow = (const float4*)(codes + (size_t)n * 64);
  double a = 0.0;
#pragma unroll
  for (int i = 0; i < 16; ++i) {
    float4 q = crow[i];
    a = fma((double)q.x, od[i*4+0], a);
    a = fma((double)q.y, od[i*4+1], a);
    a = fma((double)q.z, od[i*4+2], a);
    a = fma((double)q.w, od[i*4+3], a);
  }
  return a;
}

// ---- detect labels layout: int64 (little-endian pairs) vs int32 ----
__global__ __launch_bounds__(256) void k_detect(const int* __restrict__ labels, int N,
                                                Scal* scal) {
  __shared__ int flag;
  if (threadIdx.x == 0) flag = 0;
  __syncthreads();
  int m = N < 256 ? N : 256;
  if ((int)threadIdx.x < m && labels[2 * threadIdx.x + 1] != 0) atomicOr(&flag, 1);
  __syncthreads();
  if (threadIdx.x == 0) scal->shift = flag ? 0 : 1;  // label(n) = labels[n << shift]
}

// ---- max ||code_n||^2 ----
__global__ __launch_bounds__(256) void k_codenorm(const float* __restrict__ codes,
                                                  int N, Scal* scal) {
  int n = blockIdx.x * 256 + threadIdx.x;
  float m = 0.0f;
  if (n < N) {
    const float4* crow = (const float4*)(codes + (size_t)n * 64);
    double c2 = 0.0;
#pragma unroll
    for (int i = 0; i < 16; ++i) {
      float4 q = crow[i];
      c2 = fma((double)q.x, (double)q.x, c2);
      c2 = fma((double)q.y, (double)q.y, c2);
      c2 = fma((double)q.z, (double)q.z, c2);
      c2 = fma((double)q.w, (double)q.w, c2);
    }
    m = (float)(c2 * 1.000001);
  }
  __shared__ float red[256];
  red[threadIdx.x] = m; __syncthreads();
  for (int off = 128; off > 0; off >>= 1) {
    if (threadIdx.x < off) red[threadIdx.x] = fmaxf(red[threadIdx.x], red[threadIdx.x + off]);
    __syncthreads();
  }
  if (threadIdx.x == 0) atomicMax(&scal->cmaxsq_bits, __float_as_uint(red[0]));
}

// ---- out = x @ W in f64 (+ f32 copy), plus ||out_b||^2 ----
// 1024 thr: 16 K-chunks x 8 independent accumulators => ~128 loads in flight/CU.
__global__ __launch_bounds__(1024) void k_out(const float* __restrict__ x,
                                              const float* __restrict__ W, int D,
                                              double* __restrict__ out64,
                                              float* __restrict__ out32,
                                              double* __restrict__ B1sq) {
  int b = blockIdx.x, tid = threadIdx.x;
  int t = tid & 63, w = tid >> 6;          // w in 0..15
  int kc = D >> 4;                         // 128 for D=2048
  int k0 = w * kc;
  const float* xr = x + (size_t)b * D;
  double a[8];
#pragma unroll
  for (int j = 0; j < 8; ++j) a[j] = 0.0;
  for (int k = k0; k < k0 + kc; k += 8) {
    float4 xv0 = *(const float4*)(xr + k);
    float4 xv1 = *(const float4*)(xr + k + 4);
    float xs[8] = {xv0.x, xv0.y, xv0.z, xv0.w, xv1.x, xv1.y, xv1.z, xv1.w};
#pragma unroll
    for (int j = 0; j < 8; ++j)
      a[j] = fma((double)xs[j], (double)W[(size_t)(k + j) * 64 + t], a[j]);
  }
  __shared__ double red[1024];
  red[tid] = ((a[0] + a[1]) + (a[2] + a[3])) + ((a[4] + a[5]) + (a[6] + a[7]));
  __syncthreads();
  if (w == 0) {
    double o = 0.0;
#pragma unroll
    for (int j = 0; j < 16; ++j) o += red[t + 64 * j];
    out64[(size_t)b * 64 + t] = o;
    out32[(size_t)b * 64 + t] = (float)o;
    red[t] = o * o;                        // same-wave lanes: lockstep-safe
  }
  __syncthreads();
  if (tid == 0) {
    double s = 0.0;
    for (int i = 0; i < 64; ++i) s += red[i];
    B1sq[b] = s;
  }
}

// ---- f32 screening GEMM -> f16 scores (no LDS; out-rows via scalar broadcast) ----
__global__ __launch_bounds__(256) void k_sim(const float* __restrict__ codes,
                                             const float* __restrict__ out32,
                                             int N, unsigned short* __restrict__ simh) {
  const int tid = threadIdx.x;
  const int r0 = blockIdx.y * RG;
  const float* __restrict__ outr = out32 + (size_t)r0 * 64;
  for (int s = 0; s < SCODES; ++s) {
    const int n = blockIdx.x * CHN + s * 256 + tid;
    if (n >= N) continue;
    const float4* __restrict__ crow = (const float4*)(codes + (size_t)n * 64);
    float acc[RG];
#pragma unroll
    for (int r = 0; r < RG; ++r) acc[r] = 0.0f;
#pragma unroll 1
    for (int t4 = 0; t4 < 4; ++t4) {       // rolled: keeps body I$-resident
      float4 f0 = crow[t4*4+0], f1 = crow[t4*4+1], f2 = crow[t4*4+2], f3 = crow[t4*4+3];
      float c[16] = {f0.x,f0.y,f0.z,f0.w, f1.x,f1.y,f1.z,f1.w,
                     f2.x,f2.y,f2.z,f2.w, f3.x,f3.y,f3.z,f3.w};
#pragma unroll
      for (int r = 0; r < RG; ++r) {
        const float* __restrict__ op = outr + r * 64 + t4 * 16;  // wave-uniform -> s_load
#pragma unroll
        for (int j = 0; j < 16; ++j) acc[r] = fmaf(c[j], op[j], acc[r]);
      }
    }
#pragma unroll
    for (int r = 0; r < RG; ++r)
      simh[(size_t)(r0 + r) * N + n] = f2h(fmaf(acc[r], -0.5f, 50.0f));
  }
}

// ---- per-row 512-bucket histogram of stored f16 scores (NHCH chunks/row) ----
__global__ __launch_bounds__(256) void k_rowhist(const unsigned short* __restrict__ simh, int N,
                                                 const double* __restrict__ B1sq,
                                                 const Scal* __restrict__ scal,
                                                 unsigned* __restrict__ histg, int B) {
  __shared__ unsigned hist[NBK];
  int b = blockIdx.y, cx = blockIdx.x, tid = threadIdx.x;
  for (int i = tid; i < NBK; i += 256) hist[i] = 0u;
  __syncthreads();
  double lo, inv, bw;
  rowRange(B1sq[b], (double)__uint_as_float(scal->cmaxsq_bits), lo, inv, bw);
  int chunk = ((N + NHCH * 8 - 1) / (NHCH * 8)) * 8;   // multiple of 8
  int start = cx * chunk;
  int end = start + chunk; if (end > N) end = N;
  const unsigned short* rp = simh + (size_t)b * N;
  if (start < end) {
    const uint4* rp4 = (const uint4*)rp;
    int i8s = start >> 3, i8e = end >> 3;
    for (int i = i8s + tid; i < i8e; i += 256) {
      uint4 q = rp4[i];
      unsigned u[4] = {q.x, q.y, q.z, q.w};
#pragma unroll
      for (int k = 0; k < 4; ++k) {
        atomicAdd(&hist[bucketOf((double)h2f((unsigned short)(u[k] & 0xFFFFu)), lo, inv)], 1u);
        atomicAdd(&hist[bucketOf((double)h2f((unsigned short)(u[k] >> 16)), lo, inv)], 1u);
      }
    }
    int tail = end & ~7; if (tail < start) tail = start;
    for (int n = tail + tid; n < end; n += 256)
      atomicAdd(&hist[bucketOf((double)h2f(rp[n]), lo, inv)], 1u);
  }
  __syncthreads();
  unsigned* hg = histg + ((size_t)cx * B + b) * NBK;   // exclusive slab: plain store
  for (int i = tid; i < NBK; i += 256) hg[i] = hist[i];
}

// ---- per-row: threshold bucket -> conservative [TL, TH] window ----
__global__ __launch_bounds__(256) void k_scan(const unsigned* __restrict__ histg, int B,
                                              const double* __restrict__ B1sq,
                                              const Scal* __restrict__ scal,
                                              const int* __restrict__ Kp,
                                              double2* __restrict__ rowTH) {
  int b = blockIdx.x * 256 + threadIdx.x;
  if (b >= B) return;
  int K = Kp[0];
  unsigned cum = 0; int tb = NBK - 1;
  for (int i = 0; i < NBK; ++i) {
    unsigned c = 0;
#pragma unroll
    for (int ch = 0; ch < NHCH; ++ch) c += histg[((size_t)ch * B + b) * NBK + i];
    if (cum + c >= (unsigned)K) { tb = i; break; }
    cum += c;
  }
  double cmax = (double)__uint_as_float(scal->cmaxsq_bits);
  double lo, inv, bw; rowRange(B1sq[b], cmax, lo, inv, bw);
  double S = sqrt(B1sq[b] * cmax);
  // M bounds |v64 - h|: f32 fma-chain (gamma_63 ~3.8e-6, 2x slack) + f16 ulp (2x slack) + slop
  double M = 0.5 * S * 8e-6 + (50.0 + 0.55 * S) * 0x1p-10 + 0.01;
  double lot = lo + (double)tb * bw;
  rowTH[b] = make_double2(lot - 2.0 * M, lot + bw + 2.0 * M);
}

// ---- stream scores: below -> label hist; band -> candidates ----
__global__ __launch_bounds__(256) void k_classify(const unsigned short* __restrict__ simh, int N,
                                                  const double2* __restrict__ rowTH,
                                                  const int* __restrict__ labels,
                                                  const Scal* __restrict__ scal,
                                                  unsigned* __restrict__ belowCnt,
                                                  unsigned* __restrict__ belowTot,
                                                  unsigned* __restrict__ candCnt,
                                                  unsigned* __restrict__ cand) {
  __shared__ unsigned lab[NCLS];
  int b = blockIdx.y, tid = threadIdx.x;
  for (int i = tid; i < NCLS; i += 256) lab[i] = 0u;
  __syncthreads();
  double TL = rowTH[b].x, TH = rowTH[b].y;
  int shift = scal->shift;
  int nch = gridDim.x;
  int chunk = ((N + nch * 8 - 1) / (nch * 8)) * 8;
  int start = blockIdx.x * chunk;
  int end = start + chunk; if (end > N) end = N;
  const unsigned short* rp = simh + (size_t)b * N;
  const uint4* rp4 = (const uint4*)rp;
  if (start < N) {
    int i8s = start >> 3, i8e = end >> 3;
    for (int i = i8s + tid; i < i8e; i += 256) {
      uint4 q = rp4[i];
      unsigned u[4] = {q.x, q.y, q.z, q.w};
#pragma unroll
      for (int k = 0; k < 8; ++k) {
        unsigned short us = (unsigned short)((u[k >> 1] >> ((k & 1) * 16)) & 0xFFFFu);
        double hv = (double)h2f(us);
        int n = i * 8 + k;
        if (hv < TL) {
          atomicAdd(&lab[labels[(size_t)n << shift]], 1u);
        } else if (hv <= TH) {
          unsigned pos = atomicAdd(&candCnt[b], 1u);
          if (pos < CAPC) cand[(size_t)b * CAPC + pos] = (unsigned)n;
        }
      }
    }
    int tail = end & ~7; if (tail < start) tail = start;
    for (int n = tail + tid; n < end; n += 256) {
      double hv = (double)h2f(rp[n]);
      if (hv < TL) {
        atomicAdd(&lab[labels[(size_t)n << shift]], 1u);
      } else if (hv <= TH) {
        unsigned pos = atomicAdd(&candCnt[b], 1u);
        if (pos < CAPC) cand[(size_t)b * CAPC + pos] = (unsigned)n;
      }
    }
  }
  __syncthreads();
  for (int i = tid; i < NCLS; i += 256) {
    unsigned c = lab[i];
    if (c) { atomicAdd(&belowCnt[b * NCLS + i], c); atomicAdd(&belowTot[b], c); }
  }
}

// ---- exact f64 resolve of candidates + emit probs ----
__global__ __launch_bounds__(256) void k_final(const float* __restrict__ codes,
                                               const double* __restrict__ out64,
                                               const unsigned* __restrict__ candCnt,
                                               const unsigned* __restrict__ cand,
                                               const Scal* __restrict__ scal,
                                               const int* __restrict__ labels,
                                               const unsigned* __restrict__ belowCnt,
                                               const unsigned* __restrict__ belowTot,
                                               const int* __restrict__ Kp,
                                               float* __restrict__ outp, int N) {
  __shared__ double key[CAPC];
  __shared__ int kidx[CAPC];
  __shared__ unsigned lab[NCLS];
  int b = blockIdx.x, tid = threadIdx.x;
  int cnt = (int)candCnt[b]; if (cnt > CAPC) cnt = CAPC;
  int K = Kp[0];
  int need = K - (int)belowTot[b];
  int M = 1; while (M < cnt) M <<= 1;
  const double* od = out64 + (size_t)b * 64;
  for (int i = tid; i < M; i += 256) {
    if (i < cnt) {
      int n = (int)cand[(size_t)b * CAPC + i];
      key[i] = fma(dot1(codes, n, od), -0.5, 50.0);
      kidx[i] = n;
    } else { key[i] = __builtin_inf(); kidx[i] = 0x7FFFFFFF; }
  }
  __syncthreads();
  for (int size = 2; size <= M; size <<= 1) {
    for (int stride = size >> 1; stride > 0; stride >>= 1) {
      for (int i = tid; i < M; i += 256) {
        int j = i ^ stride;
        if (j > i) {
          double ki = key[i], kj = key[j];
          int ii = kidx[i], ij = kidx[j];
          bool up = ((i & size) == 0);
          bool sw = up ? (kj < ki || (kj == ki && ij < ii))
                       : (kj > ki || (kj == ki && ij > ii));
          if (sw) { key[i] = kj; key[j] = ki; kidx[i] = ij; kidx[j] = ii; }
        }
      }
      __syncthreads();
    }
  }
  for (int i = tid; i < NCLS; i += 256) lab[i] = 0u;
  __syncthreads();
  int shift = scal->shift;
  int take = need < cnt ? need : cnt;
  for (int i = tid; i < take; i += 256)
    atomicAdd(&lab[labels[(size_t)kidx[i] << shift]], 1u);
  __syncthreads();
  double Kd = (double)K;
  for (int c = tid; c < NCLS; c += 256)
    outp[b * NCLS + c] = (float)((double)(belowCnt[b * NCLS + c] + lab[c]) / Kd);
}

extern "C" void kernel_launch(void* const* d_in, const int* in_sizes, int n_in,
                              void* d_out, int out_size, void* d_ws, size_t ws_size,
                              hipStream_t stream) {
  const float* x     = (const float*)d_in[0];
  const float* W     = (const float*)d_in[1];
  const float* codes = (const float*)d_in[2];
  const int* labels  = (const int*)d_in[3];
  const int* Kp      = (const int*)d_in[4];

  const int B = out_size / NCLS;        // 256
  const int N = in_sizes[3];            // 100000
  const int D = in_sizes[0] / B;        // 2048

  // ws layout; [scal..candCnt] is ONE contiguous memset region.
  char* p = (char*)d_ws;
  double* out64      = (double*)p;   p += (size_t)B * 64 * sizeof(double);     // 128 KB
  double2* rowTH     = (double2*)p;  p += (size_t)B * sizeof(double2);         // 4 KB
  float* out32       = (float*)p;    p += (size_t)B * 64 * sizeof(float);      // 64 KB
  double* B1sq       = (double*)p;   p += (size_t)B * sizeof(double);          // 2 KB
  char* zbase        = p;
  Scal* scal         = (Scal*)p;     p += 64;
  unsigned* belowCnt = (unsigned*)p; p += (size_t)B * NCLS * sizeof(unsigned); // 100 KB
  unsigned* belowTot = (unsigned*)p; p += (size_t)B * sizeof(unsigned);        // 1 KB
  unsigned* candCnt  = (unsigned*)p; p += (size_t)B * sizeof(unsigned);        // 1 KB
  size_t zlen        = (size_t)(p - zbase);
  unsigned* cand     = (unsigned*)p; p += (size_t)B * CAPC * sizeof(unsigned); // 1 MB
  unsigned* histg    = (unsigned*)p; p += (size_t)NHCH * B * NBK * sizeof(unsigned); // 2 MB
  unsigned short* simh = (unsigned short*)p;                                   // 51.2 MB

  hipMemsetAsync(zbase, 0, zlen, stream);

  k_detect<<<1, 256, 0, stream>>>(labels, N, scal);
  k_codenorm<<<(N + 255) / 256, 256, 0, stream>>>(codes, N, scal);
  k_out<<<B, 1024, 0, stream>>>(x, W, D, out64, out32, B1sq);
  k_sim<<<dim3((N + CHN - 1) / CHN, B / RG), 256, 0, stream>>>(codes, out32, N, simh);
  k_rowhist<<<dim3(NHCH, B), 256, 0, stream>>>(simh, N, B1sq, scal, histg, B);
  k_scan<<<(B + 255) / 256, 256, 0, stream>>>(histg, B, B1sq, scal, Kp, rowTH);
  k_classify<<<dim3(8, B), 256, 0, stream>>>(simh, N, rowTH, labels, scal,
                                             belowCnt, belowTot, candCnt, cand);
  k_final<<<B, 256, 0, stream>>>(codes, out64, candCnt, cand, scal, labels,
                                 belowCnt, belowTot, Kp, (float*)d_out, N);
}

// Round 5
// 508.474 us; speedup vs baseline: 1.1003x; 1.0153x over previous
//
#include <hip/hip_runtime.h>
#include <hip/hip_fp16.h>

// B=256 queries, D=2048, d=64 hash dim, N=100000 database, C=100 classes,
// K=1000 SMALLEST-sim selection. Inputs f32, labels int, output f32.
//
// R5: screening GEMM on MATRIX cores (mfma_f32_16x16x32_f16) with a rigorous
// error bound M vs the f64 truth:  |v_screen - v64| <= M = 0.5*S*1.1e-3 + 0.05,
// S = ||out_b||*max||c|| (Cauchy-Schwarz; f16 cvt 2^-11 rel + f32 accum gamma).
// Two recompute passes (no 51MB score store): pass1 histograms v_screen into
// 256 buckets/row -> threshold bucket tb; pass2 reclassifies:
//   v < TL = lo_tb - 2M       => certainly in top-K  (label-counted)
//   v > TH = hi_tb + 2M       => certainly out
//   else                      => candidate (~265/row), exact f64 resolve.
// Passes need not be bit-identical: proof only uses |v_pass - v64| <= M.

#define NBK 256          // buckets per row histogram (pow2)
#define CAPC 1024        // candidate capacity per row (expected ~265)
#define MROWS 32         // out-rows per MFMA block (two 16-row tiles)
#define NCHX 128         // code-chunks (grid.x) for MFMA passes
#define NCLS 100

typedef _Float16 half8 __attribute__((ext_vector_type(8)));
typedef float floatx4 __attribute__((ext_vector_type(4)));

struct Scal { int shift; unsigned cmaxsq_bits; };

static __device__ __forceinline__ unsigned packh2(float a, float b) {
  _Float16 ha = (_Float16)a, hb = (_Float16)b;      // RNE
  unsigned short ua, ub;
  __builtin_memcpy(&ua, &ha, 2); __builtin_memcpy(&ub, &hb, 2);
  return (unsigned)ua | ((unsigned)ub << 16);
}

// shared range math (any 1-ulp discrepancy absorbed by 2M margins, M>=0.05)
static __device__ __forceinline__ void rowRange(double b1sq, double cmax,
                                                double& lo, double& inv, double& bw) {
  double hr = 0.5 * sqrt(b1sq * cmax) * 1.000001 + 9.0;  // +9 >> M: v_screen stays in range
  lo = 50.0 - hr;
  bw = (2.0 * hr) / (double)NBK;
  inv = (double)NBK / (2.0 * hr);
}

// exact f64 dot for candidate resolution (order-stable chain)
static __device__ __forceinline__ double dot1(const float* __restrict__ codes, int n,
                                              const double* __restrict__ od) {
  const float4* crow = (const float4*)(codes + (size_t)n * 64);
  double a = 0.0;
#pragma unroll
  for (int i = 0; i < 16; ++i) {
    float4 q = crow[i];
    a = fma((double)q.x, od[i*4+0], a);
    a = fma((double)q.y, od[i*4+1], a);
    a = fma((double)q.z, od[i*4+2], a);
    a = fma((double)q.w, od[i*4+3], a);
  }
  return a;
}

// ---- detect labels layout: int64 (little-endian pairs) vs int32 ----
__global__ __launch_bounds__(256) void k_detect(const int* __restrict__ labels, int N,
                                                Scal* scal) {
  __shared__ int flag;
  if (threadIdx.x == 0) flag = 0;
  __syncthreads();
  int m = N < 256 ? N : 256;
  if ((int)threadIdx.x < m && labels[2 * threadIdx.x + 1] != 0) atomicOr(&flag, 1);
  __syncthreads();
  if (threadIdx.x == 0) scal->shift = flag ? 0 : 1;  // label(n) = labels[n << shift]
}

// ---- codes f32 -> f16 (RNE) + max ||code_n||^2 ----
__global__ __launch_bounds__(256) void k_cvtnorm(const float* __restrict__ codes,
                                                 int N, int Npad, Scal* scal,
                                                 unsigned short* __restrict__ codes16) {
  int n = blockIdx.x * 256 + threadIdx.x;
  float m = 0.0f;
  if (n < N) {
    const float4* crow = (const float4*)(codes + (size_t)n * 64);
    uint4* orow = (uint4*)(codes16 + (size_t)n * 64);
    double c2 = 0.0;
#pragma unroll
    for (int i = 0; i < 8; ++i) {
      float4 qa = crow[2*i], qb = crow[2*i+1];
      c2 = fma((double)qa.x, (double)qa.x, c2); c2 = fma((double)qa.y, (double)qa.y, c2);
      c2 = fma((double)qa.z, (double)qa.z, c2); c2 = fma((double)qa.w, (double)qa.w, c2);
      c2 = fma((double)qb.x, (double)qb.x, c2); c2 = fma((double)qb.y, (double)qb.y, c2);
      c2 = fma((double)qb.z, (double)qb.z, c2); c2 = fma((double)qb.w, (double)qb.w, c2);
      uint4 o;
      o.x = packh2(qa.x, qa.y); o.y = packh2(qa.z, qa.w);
      o.z = packh2(qb.x, qb.y); o.w = packh2(qb.z, qb.w);
      orow[i] = o;
    }
    m = (float)(c2 * 1.000001);
  } else if (n < Npad) {
    uint4* orow = (uint4*)(codes16 + (size_t)n * 64);
    uint4 z = {0u,0u,0u,0u};
#pragma unroll
    for (int i = 0; i < 8; ++i) orow[i] = z;
  }
  __shared__ float red[256];
  red[threadIdx.x] = m; __syncthreads();
  for (int off = 128; off > 0; off >>= 1) {
    if (threadIdx.x < off) red[threadIdx.x] = fmaxf(red[threadIdx.x], red[threadIdx.x + off]);
    __syncthreads();
  }
  if (threadIdx.x == 0) atomicMax(&scal->cmaxsq_bits, __float_as_uint(red[0]));
}

// ---- out = x @ W in f64 (+ f16 copy for MFMA), plus ||out_b||^2 ----
__global__ __launch_bounds__(1024) void k_out(const float* __restrict__ x,
                                              const float* __restrict__ W, int D,
                                              double* __restrict__ out64,
                                              unsigned short* __restrict__ out16,
                                              double* __restrict__ B1sq) {
  int b = blockIdx.x, tid = threadIdx.x;
  int t = tid & 63, w = tid >> 6;          // w in 0..15
  int kc = D >> 4;                         // 128 for D=2048
  int k0 = w * kc;
  const float* xr = x + (size_t)b * D;
  double a[8];
#pragma unroll
  for (int j = 0; j < 8; ++j) a[j] = 0.0;
  for (int k = k0; k < k0 + kc; k += 8) {
    float4 xv0 = *(const float4*)(xr + k);
    float4 xv1 = *(const float4*)(xr + k + 4);
    float xs[8] = {xv0.x, xv0.y, xv0.z, xv0.w, xv1.x, xv1.y, xv1.z, xv1.w};
#pragma unroll
    for (int j = 0; j < 8; ++j)
      a[j] = fma((double)xs[j], (double)W[(size_t)(k + j) * 64 + t], a[j]);
  }
  __shared__ double red[1024];
  red[tid] = ((a[0] + a[1]) + (a[2] + a[3])) + ((a[4] + a[5]) + (a[6] + a[7]));
  __syncthreads();
  if (w == 0) {
    double o = 0.0;
#pragma unroll
    for (int j = 0; j < 16; ++j) o += red[t + 64 * j];
    out64[(size_t)b * 64 + t] = o;
    _Float16 h = (_Float16)(float)o;       // RNE, |o| <= ~250 well within f16
    unsigned short us; __builtin_memcpy(&us, &h, 2);
    out16[(size_t)b * 64 + t] = us;
    red[t] = o * o;                        // same-wave lanes: lockstep-safe
  }
  __syncthreads();
  if (tid == 0) {
    double s = 0.0;
    for (int i = 0; i < 64; ++i) s += red[i];
    B1sq[b] = s;
  }
}

// ---- shared MFMA tile helper: load A-frags for 2 row-tiles (m0..m0+31) ----
// mfma_f32_16x16x32_f16 layouts (m89/m120-verified family):
//   A: lane holds A[m = lane&15][k = (lane>>4)*8 + j], j=0..7
//   B: lane holds B[k = (lane>>4)*8 + j][n = lane&15]
//   D: lane reg r = D[m = (lane>>4)*4 + r][n = lane&15]
static __device__ __forceinline__ void loadA(const unsigned short* __restrict__ out16,
                                             int m0, int mr, int quad,
                                             half8& a00, half8& a01, half8& a10, half8& a11) {
  const uint4* o4 = (const uint4*)out16;   // 8 halves per uint4; row = 8 uint4
  uint4 u;
  u = o4[(size_t)(m0 + mr) * 8 + quad];          __builtin_memcpy(&a00, &u, 16);
  u = o4[(size_t)(m0 + mr) * 8 + 4 + quad];      __builtin_memcpy(&a01, &u, 16);
  u = o4[(size_t)(m0 + 16 + mr) * 8 + quad];     __builtin_memcpy(&a10, &u, 16);
  u = o4[(size_t)(m0 + 16 + mr) * 8 + 4 + quad]; __builtin_memcpy(&a11, &u, 16);
}

// ---- pass 1: MFMA screen -> per-row NBK-bucket histogram ----
__global__ __launch_bounds__(256) void k_mhist(const unsigned short* __restrict__ codes16,
                                               const unsigned short* __restrict__ out16,
                                               const double* __restrict__ B1sq,
                                               const Scal* __restrict__ scal,
                                               int N, int Npad, int cpb,
                                               unsigned* __restrict__ histg) {
  __shared__ unsigned hist[MROWS * NBK];   // 32 KB
  __shared__ float sP[MROWS], sQ[MROWS];
  int tid = threadIdx.x;
  int m0 = blockIdx.y * MROWS;
  for (int i = tid; i < MROWS * NBK; i += 256) hist[i] = 0u;
  if (tid < MROWS) {
    double lo, inv, bw;
    rowRange(B1sq[m0 + tid], (double)__uint_as_float(scal->cmaxsq_bits), lo, inv, bw);
    sP[tid] = (float)(-0.5 * inv);         // bucket = trunc(d*P + Q), monotone in v
    sQ[tid] = (float)((50.0 - lo) * inv);
  }
  __syncthreads();
  int l = tid & 63, w = tid >> 6;
  int quad = l >> 4, mr = l & 15;
  half8 a00, a01, a10, a11;
  loadA(out16, m0, mr, quad, a00, a01, a10, a11);
  float P0[4], Q0[4], P1[4], Q1[4];
#pragma unroll
  for (int r = 0; r < 4; ++r) {
    P0[r] = sP[quad*4 + r];      Q0[r] = sQ[quad*4 + r];
    P1[r] = sP[16 + quad*4 + r]; Q1[r] = sQ[16 + quad*4 + r];
  }
  int cstart = blockIdx.x * cpb;
  int cend = cstart + cpb; if (cend > N) cend = N;
  const uint4* c4 = (const uint4*)codes16;
  floatx4 z = {0.f, 0.f, 0.f, 0.f};
  for (int base = cstart; base < cend; base += 64) {
    int nrow = base + w * 16 + mr;
    int nc = nrow < Npad ? nrow : Npad - 1;
    uint4 ub0 = c4[(size_t)nc * 8 + quad];
    uint4 ub1 = c4[(size_t)nc * 8 + 4 + quad];
    half8 b0, b1;
    __builtin_memcpy(&b0, &ub0, 16); __builtin_memcpy(&b1, &ub1, 16);
    floatx4 d0 = __builtin_amdgcn_mfma_f32_16x16x32_f16(a00, b0, z, 0, 0, 0);
    d0 = __builtin_amdgcn_mfma_f32_16x16x32_f16(a01, b1, d0, 0, 0, 0);
    floatx4 d1 = __builtin_amdgcn_mfma_f32_16x16x32_f16(a10, b0, z, 0, 0, 0);
    d1 = __builtin_amdgcn_mfma_f32_16x16x32_f16(a11, b1, d1, 0, 0, 0);
    if (nrow < N) {
#pragma unroll
      for (int r = 0; r < 4; ++r) {
        int bk0 = (int)fmaf(d0[r], P0[r], Q0[r]);
        bk0 = bk0 < 0 ? 0 : (bk0 > NBK-1 ? NBK-1 : bk0);
        atomicAdd(&hist[(quad*4 + r) * NBK + bk0], 1u);
        int bk1 = (int)fmaf(d1[r], P1[r], Q1[r]);
        bk1 = bk1 < 0 ? 0 : (bk1 > NBK-1 ? NBK-1 : bk1);
        atomicAdd(&hist[(16 + quad*4 + r) * NBK + bk1], 1u);
      }
    }
  }
  __syncthreads();
  for (int i = tid; i < MROWS * NBK; i += 256) {
    unsigned c = hist[i];
    if (c) atomicAdd(&histg[(size_t)(m0 + (i >> 8)) * NBK + (i & (NBK - 1))], c);
  }
}

// ---- per-row: inclusive scan of hist -> threshold bucket -> [TL,TH] floats ----
__global__ __launch_bounds__(NBK) void k_scan(const unsigned* __restrict__ histg,
                                              const double* __restrict__ B1sq,
                                              const Scal* __restrict__ scal,
                                              const int* __restrict__ Kp,
                                              float2* __restrict__ rowTH) {
  __shared__ unsigned s[NBK];
  int b = blockIdx.x, tid = threadIdx.x;
  s[tid] = histg[(size_t)b * NBK + tid];
  __syncthreads();
  for (int off = 1; off < NBK; off <<= 1) {
    unsigned add = (tid >= off) ? s[tid - off] : 0u;
    __syncthreads();
    s[tid] += add;
    __syncthreads();
  }
  unsigned K = (unsigned)Kp[0];
  unsigned cum = s[tid], prev = tid ? s[tid - 1] : 0u;
  if (cum >= K && prev < K) {              // exactly one thread: tb = tid
    double lo, inv, bw;
    double cmax = (double)__uint_as_float(scal->cmaxsq_bits);
    rowRange(B1sq[b], cmax, lo, inv, bw);
    double S = sqrt(B1sq[b] * cmax);
    // M: f16 inputs (2*2^-11 rel) + f32 accum gamma_63, *0.5 scale, +12% + abs slack
    double M = 0.5 * S * 1.1e-3 + 0.05;
    double lot = lo + (double)tid * bw;
    rowTH[b] = make_float2((float)(lot - 2.0 * M - 1e-3),
                           (float)(lot + bw + 2.0 * M + 1e-3));
  }
}

// ---- pass 2: MFMA recompute -> below label-hist / band candidates ----
__global__ __launch_bounds__(256) void k_mclass(const unsigned short* __restrict__ codes16,
                                                const unsigned short* __restrict__ out16,
                                                const float2* __restrict__ rowTH,
                                                const int* __restrict__ labels,
                                                const Scal* __restrict__ scal,
                                                int N, int Npad, int cpb,
                                                unsigned* __restrict__ belowCnt,
                                                unsigned* __restrict__ belowTot,
                                                unsigned* __restrict__ candCnt,
                                                unsigned* __restrict__ cand) {
  __shared__ unsigned lab[MROWS * NCLS];   // 12.8 KB
  __shared__ float sTL[MROWS], sTH[MROWS];
  int tid = threadIdx.x;
  int m0 = blockIdx.y * MROWS;
  for (int i = tid; i < MROWS * NCLS; i += 256) lab[i] = 0u;
  if (tid < MROWS) {
    float2 th = rowTH[m0 + tid];
    sTL[tid] = th.x; sTH[tid] = th.y;
  }
  __syncthreads();
  int l = tid & 63, w = tid >> 6;
  int quad = l >> 4, mr = l & 15;
  half8 a00, a01, a10, a11;
  loadA(out16, m0, mr, quad, a00, a01, a10, a11);
  float TL0[4], TH0[4], TL1[4], TH1[4];
#pragma unroll
  for (int r = 0; r < 4; ++r) {
    TL0[r] = sTL[quad*4 + r];      TH0[r] = sTH[quad*4 + r];
    TL1[r] = sTL[16 + quad*4 + r]; TH1[r] = sTH[16 + quad*4 + r];
  }
  int shift = scal->shift;
  int cstart = blockIdx.x * cpb;
  int cend = cstart + cpb; if (cend > N) cend = N;
  const uint4* c4 = (const uint4*)codes16;
  floatx4 z = {0.f, 0.f, 0.f, 0.f};
  for (int base = cstart; base < cend; base += 64) {
    int nrow = base + w * 16 + mr;
    int nc = nrow < Npad ? nrow : Npad - 1;
    uint4 ub0 = c4[(size_t)nc * 8 + quad];
    uint4 ub1 = c4[(size_t)nc * 8 + 4 + quad];
    half8 b0, b1;
    __builtin_memcpy(&b0, &ub0, 16); __builtin_memcpy(&b1, &ub1, 16);
    int nl = nrow < N ? nrow : N - 1;
    int lv = labels[(size_t)nl << shift];
    floatx4 d0 = __builtin_amdgcn_mfma_f32_16x16x32_f16(a00, b0, z, 0, 0, 0);
    d0 = __builtin_amdgcn_mfma_f32_16x16x32_f16(a01, b1, d0, 0, 0, 0);
    floatx4 d1 = __builtin_amdgcn_mfma_f32_16x16x32_f16(a10, b0, z, 0, 0, 0);
    d1 = __builtin_amdgcn_mfma_f32_16x16x32_f16(a11, b1, d1, 0, 0, 0);
    if (nrow < N) {
#pragma unroll
      for (int r = 0; r < 4; ++r) {
        float v0 = fmaf(d0[r], -0.5f, 50.0f);
        if (v0 < TL0[r]) {
          atomicAdd(&lab[(quad*4 + r) * NCLS + lv], 1u);
        } else if (v0 <= TH0[r]) {
          int row = m0 + quad*4 + r;
          unsigned pos = atomicAdd(&candCnt[row], 1u);
          if (pos < CAPC) cand[(size_t)row * CAPC + pos] = (unsigned)nrow;
        }
        float v1 = fmaf(d1[r], -0.5f, 50.0f);
        if (v1 < TL1[r]) {
          atomicAdd(&lab[(16 + quad*4 + r) * NCLS + lv], 1u);
        } else if (v1 <= TH1[r]) {
          int row = m0 + 16 + quad*4 + r;
          unsigned pos = atomicAdd(&candCnt[row], 1u);
          if (pos < CAPC) cand[(size_t)row * CAPC + pos] = (unsigned)nrow;
        }
      }
    }
  }
  __syncthreads();
  for (int i = tid; i < MROWS * NCLS; i += 256) {
    unsigned c = lab[i];
    if (c) {
      int row = m0 + i / NCLS;
      atomicAdd(&belowCnt[row * NCLS + i % NCLS], c);
      atomicAdd(&belowTot[row], c);
    }
  }
}

// ---- exact f64 resolve of candidates + emit probs ----
__global__ __launch_bounds__(256) void k_final(const float* __restrict__ codes,
                                               const double* __restrict__ out64,
                                               const unsigned* __restrict__ candCnt,
                                               const unsigned* __restrict__ cand,
                                               const Scal* __restrict__ scal,
                                               const int* __restrict__ labels,
                                               const unsigned* __restrict__ belowCnt,
                                               const unsigned* __restrict__ belowTot,
                                               const int* __restrict__ Kp,
                                               float* __restrict__ outp, int N) {
  __shared__ double key[CAPC];
  __shared__ int kidx[CAPC];
  __shared__ unsigned lab[NCLS];
  int b = blockIdx.x, tid = threadIdx.x;
  int cnt = (int)candCnt[b]; if (cnt > CAPC) cnt = CAPC;
  int K = Kp[0];
  int need = K - (int)belowTot[b];
  int M = 1; while (M < cnt) M <<= 1;
  const double* od = out64 + (size_t)b * 64;
  for (int i = tid; i < M; i += 256) {
    if (i < cnt) {
      int n = (int)cand[(size_t)b * CAPC + i];
      key[i] = fma(dot1(codes, n, od), -0.5, 50.0);
      kidx[i] = n;
    } else { key[i] = __builtin_inf(); kidx[i] = 0x7FFFFFFF; }
  }
  __syncthreads();
  for (int size = 2; size <= M; size <<= 1) {
    for (int stride = size >> 1; stride > 0; stride >>= 1) {
      for (int i = tid; i < M; i += 256) {
        int j = i ^ stride;
        if (j > i) {
          double ki = key[i], kj = key[j];
          int ii = kidx[i], ij = kidx[j];
          bool up = ((i & size) == 0);
          bool sw = up ? (kj < ki || (kj == ki && ij < ii))
                       : (kj > ki || (kj == ki && ij > ii));
          if (sw) { key[i] = kj; key[j] = ki; kidx[i] = ij; kidx[j] = ii; }
        }
      }
      __syncthreads();
    }
  }
  for (int i = tid; i < NCLS; i += 256) lab[i] = 0u;
  __syncthreads();
  int shift = scal->shift;
  int take = need < cnt ? need : cnt;
  for (int i = tid; i < take; i += 256)
    atomicAdd(&lab[labels[(size_t)kidx[i] << shift]], 1u);
  __syncthreads();
  double Kd = (double)K;
  for (int c = tid; c < NCLS; c += 256)
    outp[b * NCLS + c] = (float)((double)(belowCnt[b * NCLS + c] + lab[c]) / Kd);
}

extern "C" void kernel_launch(void* const* d_in, const int* in_sizes, int n_in,
                              void* d_out, int out_size, void* d_ws, size_t ws_size,
                              hipStream_t stream) {
  const float* x     = (const float*)d_in[0];
  const float* W     = (const float*)d_in[1];
  const float* codes = (const float*)d_in[2];
  const int* labels  = (const int*)d_in[3];
  const int* Kp      = (const int*)d_in[4];

  const int B = out_size / NCLS;             // 256
  const int N = in_sizes[3];                 // 100000
  const int D = in_sizes[0] / B;             // 2048
  const int Npad = (N + 255) & ~255;         // 100096
  const int cpb = (((N + NCHX - 1) / NCHX) + 63) & ~63;  // codes per block, x64

  // ws layout; [scal .. histg] is ONE contiguous memset region (~358 KB).
  char* p = (char*)d_ws;
  double* out64      = (double*)p;   p += (size_t)B * 64 * sizeof(double);       // 128 KB
  float2* rowTH      = (float2*)p;   p += (size_t)B * sizeof(float2);            // 2 KB
  unsigned short* out16 = (unsigned short*)p; p += (size_t)B * 64 * 2;           // 32 KB
  double* B1sq       = (double*)p;   p += (size_t)B * sizeof(double);            // 2 KB
  char* zbase        = p;
  Scal* scal         = (Scal*)p;     p += 64;
  unsigned* belowCnt = (unsigned*)p; p += (size_t)B * NCLS * sizeof(unsigned);   // 100 KB
  unsigned* belowTot = (unsigned*)p; p += (size_t)B * sizeof(unsigned);          // 1 KB
  unsigned* candCnt  = (unsigned*)p; p += (size_t)B * sizeof(unsigned);          // 1 KB
  unsigned* histg    = (unsigned*)p; p += (size_t)B * NBK * sizeof(unsigned);    // 256 KB
  size_t zlen        = (size_t)(p - zbase);
  unsigned* cand     = (unsigned*)p; p += (size_t)B * CAPC * sizeof(unsigned);   // 1 MB
  unsigned short* codes16 = (unsigned short*)p;                                  // 12.8 MB

  hipMemsetAsync(zbase, 0, zlen, stream);

  k_detect<<<1, 256, 0, stream>>>(labels, N, scal);
  k_cvtnorm<<<Npad / 256, 256, 0, stream>>>(codes, N, Npad, scal, codes16);
  k_out<<<B, 1024, 0, stream>>>(x, W, D, out64, out16, B1sq);
  k_mhist<<<dim3(NCHX, B / MROWS), 256, 0, stream>>>(codes16, out16, B1sq, scal,
                                                     N, Npad, cpb, histg);
  k_scan<<<B, NBK, 0, stream>>>(histg, B1sq, scal, Kp, rowTH);
  k_mclass<<<dim3(NCHX, B / MROWS), 256, 0, stream>>>(codes16, out16, rowTH, labels, scal,
                                                      N, Npad, cpb,
                                                      belowCnt, belowTot, candCnt, cand);
  k_final<<<B, 256, 0, stream>>>(codes, out64, candCnt, cand, scal, labels,
                                 belowCnt, belowTot, Kp, (float*)d_out, N);
}

// Round 6
// 199.767 us; speedup vs baseline: 2.8005x; 2.5453x over previous
//
#include <hip/hip_runtime.h>
#include <hip/hip_fp16.h>

// B=256 queries, D=2048, d=64 hash dim, N=100000 database, C=100 classes,
// K=1000 SMALLEST-sim selection. Inputs f32, labels int, output f32.
//
// MFMA screen (mfma_f32_16x16x32_f16) with rigorous error bound M vs f64
// truth: |v_screen - v64| <= M = 0.5*S*1.1e-3 + 0.05, S = ||out_b||*max||c||.
// pass1 histograms v_screen (256 buckets/row) -> threshold bucket tb; pass2:
//   v < TL = lo_tb - 2M  => certainly in top-K (label-counted)
//   v > TH = hi_tb + 2M  => certainly out
//   else                 => candidate (~265/row), exact f64 resolve in k_final.
//
// R6: NO return-dependent global atomics (R5: 98% stall on packed candCnt
// L2 atomics). All cross-block state goes to private per-(chunk,row) slabs
// with plain stores; candidate slots come from LDS atomics; k_final gathers.

#define NBK 256          // buckets per row histogram (pow2)
#define CAPC 1024        // per-row candidate capacity at k_final (expected ~265)
#define CAPB 64          // per-(chunk,row) segment capacity (expected ~4)
#define MROWS 32         // out-rows per MFMA block (two 16-row tiles)
#define NCHX 64          // code-chunks (grid.x) for MFMA passes
#define NCLS 100

typedef _Float16 half8 __attribute__((ext_vector_type(8)));
typedef float floatx4 __attribute__((ext_vector_type(4)));

struct Scal { int shift; unsigned cmaxsq_bits; };

static __device__ __forceinline__ unsigned packh2(float a, float b) {
  _Float16 ha = (_Float16)a, hb = (_Float16)b;      // RNE
  unsigned short ua, ub;
  __builtin_memcpy(&ua, &ha, 2); __builtin_memcpy(&ub, &hb, 2);
  return (unsigned)ua | ((unsigned)ub << 16);
}

// shared range math (1-ulp discrepancies absorbed by 2M margins, M>=0.05)
static __device__ __forceinline__ void rowRange(double b1sq, double cmax,
                                                double& lo, double& inv, double& bw) {
  double hr = 0.5 * sqrt(b1sq * cmax) * 1.000001 + 9.0;  // +9 >> M
  lo = 50.0 - hr;
  bw = (2.0 * hr) / (double)NBK;
  inv = (double)NBK / (2.0 * hr);
}

// exact f64 dot for candidate resolution (order-stable chain)
static __device__ __forceinline__ double dot1(const float* __restrict__ codes, int n,
                                              const double* __restrict__ od) {
  const float4* crow = (const float4*)(codes + (size_t)n * 64);
  double a = 0.0;
#pragma unroll
  for (int i = 0; i < 16; ++i) {
    float4 q = crow[i];
    a = fma((double)q.x, od[i*4+0], a);
    a = fma((double)q.y, od[i*4+1], a);
    a = fma((double)q.z, od[i*4+2], a);
    a = fma((double)q.w, od[i*4+3], a);
  }
  return a;
}

// ---- detect labels layout: int64 (little-endian pairs) vs int32 ----
__global__ __launch_bounds__(256) void k_detect(const int* __restrict__ labels, int N,
                                                Scal* scal) {
  __shared__ int flag;
  if (threadIdx.x == 0) flag = 0;
  __syncthreads();
  int m = N < 256 ? N : 256;
  if ((int)threadIdx.x < m && labels[2 * threadIdx.x + 1] != 0) atomicOr(&flag, 1);
  __syncthreads();
  if (threadIdx.x == 0) scal->shift = flag ? 0 : 1;  // label(n) = labels[n << shift]
}

// ---- codes f32 -> f16 (RNE) + max ||code_n||^2 ----
__global__ __launch_bounds__(256) void k_cvtnorm(const float* __restrict__ codes,
                                                 int N, int Npad, Scal* scal,
                                                 unsigned short* __restrict__ codes16) {
  int n = blockIdx.x * 256 + threadIdx.x;
  float m = 0.0f;
  if (n < N) {
    const float4* crow = (const float4*)(codes + (size_t)n * 64);
    uint4* orow = (uint4*)(codes16 + (size_t)n * 64);
    double c2 = 0.0;
#pragma unroll
    for (int i = 0; i < 8; ++i) {
      float4 qa = crow[2*i], qb = crow[2*i+1];
      c2 = fma((double)qa.x, (double)qa.x, c2); c2 = fma((double)qa.y, (double)qa.y, c2);
      c2 = fma((double)qa.z, (double)qa.z, c2); c2 = fma((double)qa.w, (double)qa.w, c2);
      c2 = fma((double)qb.x, (double)qb.x, c2); c2 = fma((double)qb.y, (double)qb.y, c2);
      c2 = fma((double)qb.z, (double)qb.z, c2); c2 = fma((double)qb.w, (double)qb.w, c2);
      uint4 o;
      o.x = packh2(qa.x, qa.y); o.y = packh2(qa.z, qa.w);
      o.z = packh2(qb.x, qb.y); o.w = packh2(qb.z, qb.w);
      orow[i] = o;
    }
    m = (float)(c2 * 1.000001);
  } else if (n < Npad) {
    uint4* orow = (uint4*)(codes16 + (size_t)n * 64);
    uint4 z = {0u,0u,0u,0u};
#pragma unroll
    for (int i = 0; i < 8; ++i) orow[i] = z;
  }
  __shared__ float red[256];
  red[threadIdx.x] = m; __syncthreads();
  for (int off = 128; off > 0; off >>= 1) {
    if (threadIdx.x < off) red[threadIdx.x] = fmaxf(red[threadIdx.x], red[threadIdx.x + off]);
    __syncthreads();
  }
  if (threadIdx.x == 0) atomicMax(&scal->cmaxsq_bits, __float_as_uint(red[0]));
}

// ---- out = x @ W in f64 (+ f16 copy for MFMA), plus ||out_b||^2 ----
__global__ __launch_bounds__(1024) void k_out(const float* __restrict__ x,
                                              const float* __restrict__ W, int D,
                                              double* __restrict__ out64,
                                              unsigned short* __restrict__ out16,
                                              double* __restrict__ B1sq) {
  int b = blockIdx.x, tid = threadIdx.x;
  int t = tid & 63, w = tid >> 6;          // w in 0..15
  int kc = D >> 4;                         // 128 for D=2048
  int k0 = w * kc;
  const float* xr = x + (size_t)b * D;
  double a[8];
#pragma unroll
  for (int j = 0; j < 8; ++j) a[j] = 0.0;
  for (int k = k0; k < k0 + kc; k += 8) {
    float4 xv0 = *(const float4*)(xr + k);
    float4 xv1 = *(const float4*)(xr + k + 4);
    float xs[8] = {xv0.x, xv0.y, xv0.z, xv0.w, xv1.x, xv1.y, xv1.z, xv1.w};
#pragma unroll
    for (int j = 0; j < 8; ++j)
      a[j] = fma((double)xs[j], (double)W[(size_t)(k + j) * 64 + t], a[j]);
  }
  __shared__ double red[1024];
  red[tid] = ((a[0] + a[1]) + (a[2] + a[3])) + ((a[4] + a[5]) + (a[6] + a[7]));
  __syncthreads();
  if (w == 0) {
    double o = 0.0;
#pragma unroll
    for (int j = 0; j < 16; ++j) o += red[t + 64 * j];
    out64[(size_t)b * 64 + t] = o;
    _Float16 h = (_Float16)(float)o;       // RNE
    unsigned short us; __builtin_memcpy(&us, &h, 2);
    out16[(size_t)b * 64 + t] = us;
    red[t] = o * o;                        // same-wave lanes: lockstep-safe
  }
  __syncthreads();
  if (tid == 0) {
    double s = 0.0;
    for (int i = 0; i < 64; ++i) s += red[i];
    B1sq[b] = s;
  }
}

// ---- MFMA A-fragment loader (mfma_f32_16x16x32_f16 layout, m89-verified):
//   A: lane holds A[m = lane&15][k = (lane>>4)*8 + j]; D: reg r = D[(lane>>4)*4+r][lane&15]
static __device__ __forceinline__ void loadA(const unsigned short* __restrict__ out16,
                                             int m0, int mr, int quad,
                                             half8& a00, half8& a01, half8& a10, half8& a11) {
  const uint4* o4 = (const uint4*)out16;
  uint4 u;
  u = o4[(size_t)(m0 + mr) * 8 + quad];          __builtin_memcpy(&a00, &u, 16);
  u = o4[(size_t)(m0 + mr) * 8 + 4 + quad];      __builtin_memcpy(&a01, &u, 16);
  u = o4[(size_t)(m0 + 16 + mr) * 8 + quad];     __builtin_memcpy(&a10, &u, 16);
  u = o4[(size_t)(m0 + 16 + mr) * 8 + 4 + quad]; __builtin_memcpy(&a11, &u, 16);
}

// ---- pass 1: MFMA screen -> per-(chunk,row) private histogram slab ----
__global__ __launch_bounds__(256) void k_mhist(const unsigned short* __restrict__ codes16,
                                               const unsigned short* __restrict__ out16,
                                               const double* __restrict__ B1sq,
                                               const Scal* __restrict__ scal,
                                               int N, int Npad, int cpb, int B,
                                               unsigned* __restrict__ histg) {
  __shared__ unsigned hist[MROWS * NBK];   // 32 KB
  __shared__ float sP[MROWS], sQ[MROWS];
  int tid = threadIdx.x;
  int m0 = blockIdx.y * MROWS, cx = blockIdx.x;
  for (int i = tid; i < MROWS * NBK; i += 256) hist[i] = 0u;
  if (tid < MROWS) {
    double lo, inv, bw;
    rowRange(B1sq[m0 + tid], (double)__uint_as_float(scal->cmaxsq_bits), lo, inv, bw);
    sP[tid] = (float)(-0.5 * inv);         // bucket = trunc(d*P + Q), monotone in v
    sQ[tid] = (float)((50.0 - lo) * inv);
  }
  __syncthreads();
  int l = tid & 63, w = tid >> 6;
  int quad = l >> 4, mr = l & 15;
  half8 a00, a01, a10, a11;
  loadA(out16, m0, mr, quad, a00, a01, a10, a11);
  float P0[4], Q0[4], P1[4], Q1[4];
#pragma unroll
  for (int r = 0; r < 4; ++r) {
    P0[r] = sP[quad*4 + r];      Q0[r] = sQ[quad*4 + r];
    P1[r] = sP[16 + quad*4 + r]; Q1[r] = sQ[16 + quad*4 + r];
  }
  int cstart = cx * cpb;
  int cend = cstart + cpb; if (cend > N) cend = N;
  const uint4* c4 = (const uint4*)codes16;
  floatx4 z = {0.f, 0.f, 0.f, 0.f};
  for (int base = cstart; base < cend; base += 64) {
    int nrow = base + w * 16 + mr;
    int nc = nrow < Npad ? nrow : Npad - 1;
    uint4 ub0 = c4[(size_t)nc * 8 + quad];
    uint4 ub1 = c4[(size_t)nc * 8 + 4 + quad];
    half8 b0, b1;
    __builtin_memcpy(&b0, &ub0, 16); __builtin_memcpy(&b1, &ub1, 16);
    floatx4 d0 = __builtin_amdgcn_mfma_f32_16x16x32_f16(a00, b0, z, 0, 0, 0);
    d0 = __builtin_amdgcn_mfma_f32_16x16x32_f16(a01, b1, d0, 0, 0, 0);
    floatx4 d1 = __builtin_amdgcn_mfma_f32_16x16x32_f16(a10, b0, z, 0, 0, 0);
    d1 = __builtin_amdgcn_mfma_f32_16x16x32_f16(a11, b1, d1, 0, 0, 0);
    if (nrow < N) {
#pragma unroll
      for (int r = 0; r < 4; ++r) {
        int bk0 = (int)fmaf(d0[r], P0[r], Q0[r]);
        bk0 = bk0 < 0 ? 0 : (bk0 > NBK-1 ? NBK-1 : bk0);
        atomicAdd(&hist[(quad*4 + r) * NBK + bk0], 1u);   // LDS: local, fast
        int bk1 = (int)fmaf(d1[r], P1[r], Q1[r]);
        bk1 = bk1 < 0 ? 0 : (bk1 > NBK-1 ? NBK-1 : bk1);
        atomicAdd(&hist[(16 + quad*4 + r) * NBK + bk1], 1u);
      }
    }
  }
  __syncthreads();
  // exclusive slab, plain coalesced stores (no global atomics)
  for (int i = tid; i < MROWS * NBK; i += 256)
    histg[((size_t)cx * B + (m0 + (i >> 8))) * NBK + (i & (NBK - 1))] = hist[i];
}

// ---- per-row: sum chunk slabs, scan -> threshold bucket -> [TL,TH] ----
__global__ __launch_bounds__(NBK) void k_scan(const unsigned* __restrict__ histg, int B,
                                              const double* __restrict__ B1sq,
                                              const Scal* __restrict__ scal,
                                              const int* __restrict__ Kp,
                                              float2* __restrict__ rowTH) {
  __shared__ unsigned s[NBK];
  int b = blockIdx.x, tid = threadIdx.x;
  unsigned acc = 0;
  for (int cx = 0; cx < NCHX; ++cx)
    acc += histg[((size_t)cx * B + b) * NBK + tid];      // coalesced
  s[tid] = acc;
  __syncthreads();
  for (int off = 1; off < NBK; off <<= 1) {
    unsigned add = (tid >= off) ? s[tid - off] : 0u;
    __syncthreads();
    s[tid] += add;
    __syncthreads();
  }
  unsigned K = (unsigned)Kp[0];
  unsigned cum = s[tid], prev = tid ? s[tid - 1] : 0u;
  if (cum >= K && prev < K) {              // exactly one thread: tb = tid
    double lo, inv, bw;
    double cmax = (double)__uint_as_float(scal->cmaxsq_bits);
    rowRange(B1sq[b], cmax, lo, inv, bw);
    double S = sqrt(B1sq[b] * cmax);
    double M = 0.5 * S * 1.1e-3 + 0.05;    // f16 cvt + f32 accum bound
    double lot = lo + (double)tid * bw;
    rowTH[b] = make_float2((float)(lot - 2.0 * M - 1e-3),
                           (float)(lot + bw + 2.0 * M + 1e-3));
  }
}

// ---- pass 2: MFMA recompute -> below label-hist / private candidate segments ----
__global__ __launch_bounds__(256) void k_mclass(const unsigned short* __restrict__ codes16,
                                                const unsigned short* __restrict__ out16,
                                                const float2* __restrict__ rowTH,
                                                const int* __restrict__ labels,
                                                const Scal* __restrict__ scal,
                                                int N, int Npad, int cpb, int B,
                                                unsigned* __restrict__ belowCnt,
                                                unsigned* __restrict__ ccnt,
                                                unsigned* __restrict__ cand) {
  __shared__ unsigned lab[MROWS * NCLS];   // 12.8 KB
  __shared__ unsigned lcnt[MROWS];
  __shared__ float sTL[MROWS], sTH[MROWS];
  int tid = threadIdx.x;
  int m0 = blockIdx.y * MROWS, cx = blockIdx.x;
  for (int i = tid; i < MROWS * NCLS; i += 256) lab[i] = 0u;
  if (tid < MROWS) {
    lcnt[tid] = 0u;
    float2 th = rowTH[m0 + tid];
    sTL[tid] = th.x; sTH[tid] = th.y;
  }
  __syncthreads();
  int l = tid & 63, w = tid >> 6;
  int quad = l >> 4, mr = l & 15;
  half8 a00, a01, a10, a11;
  loadA(out16, m0, mr, quad, a00, a01, a10, a11);
  float TL0[4], TH0[4], TL1[4], TH1[4];
#pragma unroll
  for (int r = 0; r < 4; ++r) {
    TL0[r] = sTL[quad*4 + r];      TH0[r] = sTH[quad*4 + r];
    TL1[r] = sTL[16 + quad*4 + r]; TH1[r] = sTH[16 + quad*4 + r];
  }
  int shift = scal->shift;
  int cstart = cx * cpb;
  int cend = cstart + cpb; if (cend > N) cend = N;
  const uint4* c4 = (const uint4*)codes16;
  floatx4 z = {0.f, 0.f, 0.f, 0.f};
  for (int base = cstart; base < cend; base += 64) {
    int nrow = base + w * 16 + mr;
    int nc = nrow < Npad ? nrow : Npad - 1;
    uint4 ub0 = c4[(size_t)nc * 8 + quad];
    uint4 ub1 = c4[(size_t)nc * 8 + 4 + quad];
    half8 b0, b1;
    __builtin_memcpy(&b0, &ub0, 16); __builtin_memcpy(&b1, &ub1, 16);
    int nl = nrow < N ? nrow : N - 1;
    int lv = labels[(size_t)nl << shift];
    floatx4 d0 = __builtin_amdgcn_mfma_f32_16x16x32_f16(a00, b0, z, 0, 0, 0);
    d0 = __builtin_amdgcn_mfma_f32_16x16x32_f16(a01, b1, d0, 0, 0, 0);
    floatx4 d1 = __builtin_amdgcn_mfma_f32_16x16x32_f16(a10, b0, z, 0, 0, 0);
    d1 = __builtin_amdgcn_mfma_f32_16x16x32_f16(a11, b1, d1, 0, 0, 0);
    if (nrow < N) {
#pragma unroll
      for (int r = 0; r < 4; ++r) {
        int rl0 = quad*4 + r, rl1 = 16 + quad*4 + r;
        float v0 = fmaf(d0[r], -0.5f, 50.0f);
        if (v0 < TL0[r]) {
          atomicAdd(&lab[rl0 * NCLS + lv], 1u);                  // LDS
        } else if (v0 <= TH0[r]) {
          unsigned pos = atomicAdd(&lcnt[rl0], 1u);              // LDS, local
          if (pos < CAPB)
            cand[((size_t)cx * B + (m0 + rl0)) * CAPB + pos] = (unsigned)nrow;
        }
        float v1 = fmaf(d1[r], -0.5f, 50.0f);
        if (v1 < TL1[r]) {
          atomicAdd(&lab[rl1 * NCLS + lv], 1u);
        } else if (v1 <= TH1[r]) {
          unsigned pos = atomicAdd(&lcnt[rl1], 1u);
          if (pos < CAPB)
            cand[((size_t)cx * B + (m0 + rl1)) * CAPB + pos] = (unsigned)nrow;
        }
      }
    }
  }
  __syncthreads();
  if (tid < MROWS) {
    unsigned c = lcnt[tid];
    ccnt[(size_t)cx * B + (m0 + tid)] = c < CAPB ? c : CAPB;     // plain store
  }
  // below-class merge: fire-and-forget atomics (no return -> no wave stall)
  for (int i = tid; i < MROWS * NCLS; i += 256) {
    unsigned c = lab[i];
    if (c) atomicAdd(&belowCnt[(m0 + i / NCLS) * NCLS + i % NCLS], c);
  }
}

// ---- gather segments, exact f64 resolve, emit probs ----
__global__ __launch_bounds__(256) void k_final(const float* __restrict__ codes,
                                               const double* __restrict__ out64,
                                               const unsigned* __restrict__ ccnt,
                                               const unsigned* __restrict__ cand,
                                               const Scal* __restrict__ scal,
                                               const int* __restrict__ labels,
                                               const unsigned* __restrict__ belowCnt,
                                               const int* __restrict__ Kp,
                                               float* __restrict__ outp, int B) {
  __shared__ double key[CAPC];
  __shared__ int kidx[CAPC];
  __shared__ unsigned lab[NCLS];
  __shared__ int soff[NCHX + 1];
  __shared__ unsigned btot;
  int b = blockIdx.x, tid = threadIdx.x;
  if (tid == 0) btot = 0u;
  if (tid < NCHX) soff[tid + 1] = (int)ccnt[(size_t)tid * B + b];
  __syncthreads();
  if (tid == 0) {
    soff[0] = 0;
    for (int s = 0; s < NCHX; ++s) {
      int nx = soff[s] + soff[s + 1];
      soff[s + 1] = nx < CAPC ? nx : CAPC;
    }
  }
  // belowTot = sum of per-class below counts
  for (int c = tid; c < NCLS; c += 256) {
    unsigned v = belowCnt[b * NCLS + c];
    if (v) atomicAdd(&btot, v);
  }
  __syncthreads();
  int cnt = soff[NCHX];
  // gather: one thread per segment (avg ~4 entries each)
  for (int s = tid; s < NCHX; s += 256) {
    int c0 = soff[s], c1 = soff[s + 1];
    const unsigned* seg = cand + ((size_t)s * B + b) * CAPB;
    for (int j = 0; j < c1 - c0; ++j) kidx[c0 + j] = (int)seg[j];
  }
  __syncthreads();
  int K = Kp[0];
  int need = K - (int)btot;
  int M = 1; while (M < cnt) M <<= 1;
  const double* od = out64 + (size_t)b * 64;
  for (int i = tid; i < M; i += 256) {
    if (i < cnt) {
      key[i] = fma(dot1(codes, kidx[i], od), -0.5, 50.0);
    } else { key[i] = __builtin_inf(); kidx[i] = 0x7FFFFFFF; }
  }
  __syncthreads();
  for (int size = 2; size <= M; size <<= 1) {
    for (int stride = size >> 1; stride > 0; stride >>= 1) {
      for (int i = tid; i < M; i += 256) {
        int j = i ^ stride;
        if (j > i) {
          double ki = key[i], kj = key[j];
          int ii = kidx[i], ij = kidx[j];
          bool up = ((i & size) == 0);
          bool sw = up ? (kj < ki || (kj == ki && ij < ii))
                       : (kj > ki || (kj == ki && ij > ii));
          if (sw) { key[i] = kj; key[j] = ki; kidx[i] = ij; kidx[j] = ii; }
        }
      }
      __syncthreads();
    }
  }
  for (int i = tid; i < NCLS; i += 256) lab[i] = 0u;
  __syncthreads();
  int shift = scal->shift;
  int take = need < cnt ? need : cnt;
  if (take < 0) take = 0;
  for (int i = tid; i < take; i += 256)
    atomicAdd(&lab[labels[(size_t)kidx[i] << shift]], 1u);
  __syncthreads();
  double Kd = (double)K;
  for (int c = tid; c < NCLS; c += 256)
    outp[b * NCLS + c] = (float)((double)(belowCnt[b * NCLS + c] + lab[c]) / Kd);
}

extern "C" void kernel_launch(void* const* d_in, const int* in_sizes, int n_in,
                              void* d_out, int out_size, void* d_ws, size_t ws_size,
                              hipStream_t stream) {
  const float* x     = (const float*)d_in[0];
  const float* W     = (const float*)d_in[1];
  const float* codes = (const float*)d_in[2];
  const int* labels  = (const int*)d_in[3];
  const int* Kp      = (const int*)d_in[4];

  const int B = out_size / NCLS;             // 256
  const int N = in_sizes[3];                 // 100000
  const int D = in_sizes[0] / B;             // 2048
  const int Npad = (N + 255) & ~255;         // 100096
  const int cpb = (((N + NCHX - 1) / NCHX) + 63) & ~63;  // 1600 codes per chunk

  // ws layout; only [scal, belowCnt] needs zeroing (contiguous memset).
  char* p = (char*)d_ws;
  double* out64      = (double*)p;   p += (size_t)B * 64 * sizeof(double);       // 128 KB
  float2* rowTH      = (float2*)p;   p += (size_t)B * sizeof(float2);            // 2 KB
  unsigned short* out16 = (unsigned short*)p; p += (size_t)B * 64 * 2;           // 32 KB
  double* B1sq       = (double*)p;   p += (size_t)B * sizeof(double);            // 2 KB
  char* zbase        = p;
  Scal* scal         = (Scal*)p;     p += 64;
  unsigned* belowCnt = (unsigned*)p; p += (size_t)B * NCLS * sizeof(unsigned);   // 100 KB
  size_t zlen        = (size_t)(p - zbase);
  unsigned* ccnt     = (unsigned*)p; p += (size_t)NCHX * B * sizeof(unsigned);   // 64 KB
  unsigned* cand     = (unsigned*)p; p += (size_t)NCHX * B * CAPB * sizeof(unsigned); // 4 MB
  unsigned* histg    = (unsigned*)p; p += (size_t)NCHX * B * NBK * sizeof(unsigned);  // 16 MB
  unsigned short* codes16 = (unsigned short*)p;                                  // 12.8 MB

  hipMemsetAsync(zbase, 0, zlen, stream);

  k_detect<<<1, 256, 0, stream>>>(labels, N, scal);
  k_cvtnorm<<<Npad / 256, 256, 0, stream>>>(codes, N, Npad, scal, codes16);
  k_out<<<B, 1024, 0, stream>>>(x, W, D, out64, out16, B1sq);
  k_mhist<<<dim3(NCHX, B / MROWS), 256, 0, stream>>>(codes16, out16, B1sq, scal,
                                                     N, Npad, cpb, B, histg);
  k_scan<<<B, NBK, 0, stream>>>(histg, B, B1sq, scal, Kp, rowTH);
  k_mclass<<<dim3(NCHX, B / MROWS), 256, 0, stream>>>(codes16, out16, rowTH, labels, scal,
                                                      N, Npad, cpb, B,
                                                      belowCnt, ccnt, cand);
  k_final<<<B, 256, 0, stream>>>(codes, out64, ccnt, cand, scal, labels,
                                 belowCnt, Kp, (float*)d_out, B);
}